// Round 2
// 688.675 us; speedup vs baseline: 1.0688x; 1.0688x over previous
//
#include <hip/hip_runtime.h>
#include <stdint.h>

#define SEQ 4096
#define DM  1024
#define NB  4
#define QSCALE 0.06f

typedef __attribute__((ext_vector_type(8))) short short8;
typedef __attribute__((ext_vector_type(4))) float floatx4;

__device__ __forceinline__ unsigned short f2bf(float f) {
  union { float f; unsigned int u; } v; v.f = f;
  unsigned int u = v.u;
  u += 0x7FFFu + ((u >> 16) & 1u);
  return (unsigned short)(u >> 16);
}

__device__ __forceinline__ void async16(const void* g, void* l) {
  __builtin_amdgcn_global_load_lds(
      (const __attribute__((address_space(1))) void*)g,
      (__attribute__((address_space(3))) void*)l, 16, 0, 0);
}

// ---------------- fp32 -> bf16 convert (8 elems/thread) ----------------
__global__ void cvt_bf16(const float* __restrict__ in,
                         unsigned short* __restrict__ out, int n) {
  int i = (blockIdx.x * 256 + threadIdx.x) * 8;
  if (i >= n) return;
  const float4* p = (const float4*)(in + i);
  float4 a = p[0], b = p[1];
  short8 o;
  o[0] = (short)f2bf(a.x); o[1] = (short)f2bf(a.y);
  o[2] = (short)f2bf(a.z); o[3] = (short)f2bf(a.w);
  o[4] = (short)f2bf(b.x); o[5] = (short)f2bf(b.y);
  o[6] = (short)f2bf(b.z); o[7] = (short)f2bf(b.w);
  *(short8*)(out + i) = o;
}

// ---------------- 256x256 bf16 GEMM, C = A * W^T, K=1024 ----------------
// 8 waves (2Mx4N), BK=32, 4 LDS buffers (128 KiB), prefetch depth 3,
// counted vmcnt(8) at K-tile boundaries (never drains to 0 in steady state),
// raw s_barrier + s_setprio around MFMA clusters.
// Safety: tile t reads buf[t&3]; tile t+3 staged during tile t into
// buf[(t+3)&3], which was last read at tile t-1 and whose reads completed
// before the (t-1 -> t) boundary barrier; vmcnt(8) at the boundary leaves
// only {t+2, t+3} loads (8 per wave) outstanding => tile t+1 fully landed
// for ALL waves once every wave passes the boundary barrier.
// LDS dest for global_load_lds is WAVE-UNIFORM base (+ HW lane*16B):
// wave wid's base = lds + buf*16384 + half + wid*512, so lane l lands at
// lds + tid*8 — linear [128][32] row-major per half-tile. BK=32 => 64-B
// rows => fragment ds_read_b128 hits all 32 banks uniformly (no swizzle
// needed; the 16/32-way conflict pathology needs >=128-B rows).
template <bool OUT_BF16, int MT>
__global__ __launch_bounds__(512, 2) void gemm256(
    const unsigned short* __restrict__ A, const unsigned short* __restrict__ W,
    void* __restrict__ Cout, float alpha, long ldc) {
  __shared__ __align__(16) unsigned short lds[4 * 16384];
  const int K = 1024;
  const int NKT = 32;  // K / 32
  int tid = threadIdx.x;
  int lane = tid & 63;
  int wid = tid >> 6;
  int wr = wid >> 2, wc = wid & 3;

  // bijective XCD swizzle, nwg = 256 (divisible by 8)
  int bid = blockIdx.x;
  int raw = ((bid & 7) << 5) | (bid >> 3);
  int bx = raw % MT;
  int by = raw / MT;
  long brow = (long)bx * 256;
  long bcol = (long)by * 256;

  floatx4 acc[8][4];
#pragma unroll
  for (int i = 0; i < 8; i++)
#pragma unroll
    for (int j = 0; j < 4; j++) acc[i][j] = (floatx4){0.f, 0.f, 0.f, 0.f};

  // staging: thread t -> row (t>>2), 16B chunk (t&3) of a 128x32 half-tile
  const unsigned short* Ag = A + (brow + (tid >> 2)) * K + (tid & 3) * 8;
  const unsigned short* Wg = W + (bcol + (tid >> 2)) * K + (tid & 3) * 8;
  unsigned short* ldsW = lds + wid * 512;  // wave-uniform LDS dest base

  // fragment read offsets (ushort units; row stride 32)
  int aRd = (wr * 128 + (lane & 15)) * 32 + (lane >> 4) * 8;
  int bRd = (wc * 64 + (lane & 15)) * 32 + (lane >> 4) * 8;

  // prologue: stage tiles 0,1,2 (12 wave-loads)
#pragma unroll
  for (int tt = 0; tt < 3; tt++) {
    unsigned short* d = ldsW + tt * 16384;
    const unsigned short* a = Ag + tt * 32;
    const unsigned short* w = Wg + tt * 32;
    async16(a, d);
    async16(a + 128 * K, d + 4096);
    async16(w, d + 8192);
    async16(w + 128 * K, d + 12288);
  }
  asm volatile("s_waitcnt vmcnt(8)" ::: "memory");  // tile 0 landed
  __builtin_amdgcn_s_barrier();

  for (int t = 0; t < NKT; ++t) {
    const unsigned short* bufA = lds + (t & 3) * 16384;
    const unsigned short* bufB = bufA + 8192;
    short8 a0[4], b0[4], a1[4];
    // ---- phase A: rows [wr*128, wr*128+64) ----
#pragma unroll
    for (int mt = 0; mt < 4; mt++)
      a0[mt] = *(const short8*)(bufA + aRd + mt * 512);
#pragma unroll
    for (int nt = 0; nt < 4; nt++)
      b0[nt] = *(const short8*)(bufB + bRd + nt * 512);
    if (t + 3 < NKT) {  // stage A-halves of tile t+3
      unsigned short* d = ldsW + ((t + 3) & 3) * 16384;
      const unsigned short* a = Ag + (t + 3) * 32;
      async16(a, d);
      async16(a + 128 * K, d + 4096);
    }
    __builtin_amdgcn_s_barrier();
    __builtin_amdgcn_s_setprio(1);
#pragma unroll
    for (int mt = 0; mt < 4; mt++)
#pragma unroll
      for (int nt = 0; nt < 4; nt++)
        acc[mt][nt] = __builtin_amdgcn_mfma_f32_16x16x32_bf16(
            a0[mt], b0[nt], acc[mt][nt], 0, 0, 0);
    __builtin_amdgcn_s_setprio(0);
    __builtin_amdgcn_s_barrier();
    // ---- phase B: rows [wr*128+64, wr*128+128) ----
#pragma unroll
    for (int mt = 0; mt < 4; mt++)
      a1[mt] = *(const short8*)(bufA + aRd + 2048 + mt * 512);
    if (t + 3 < NKT) {  // stage B-halves of tile t+3
      unsigned short* d = ldsW + ((t + 3) & 3) * 16384;
      const unsigned short* w = Wg + (t + 3) * 32;
      async16(w, d + 8192);
      async16(w + 128 * K, d + 12288);
    }
    __builtin_amdgcn_s_barrier();
    __builtin_amdgcn_s_setprio(1);
#pragma unroll
    for (int mt = 0; mt < 4; mt++)
#pragma unroll
      for (int nt = 0; nt < 4; nt++)
        acc[4 + mt][nt] = __builtin_amdgcn_mfma_f32_16x16x32_bf16(
            a1[mt], b0[nt], acc[4 + mt][nt], 0, 0, 0);
    __builtin_amdgcn_s_setprio(0);
    // ---- K-tile boundary: counted wait (tile t+1 guaranteed landed) ----
    if (t < NKT - 3)
      asm volatile("s_waitcnt vmcnt(8)" ::: "memory");
    else if (t == NKT - 3)
      asm volatile("s_waitcnt vmcnt(4)" ::: "memory");
    else
      asm volatile("s_waitcnt vmcnt(0)" ::: "memory");
    __builtin_amdgcn_s_barrier();
  }

  long crow = brow + wr * 128 + (lane >> 4) * 4;
  long ccol = bcol + wc * 64 + (lane & 15);
#pragma unroll
  for (int mt = 0; mt < 8; mt++)
#pragma unroll
    for (int nt = 0; nt < 4; nt++)
#pragma unroll
      for (int r = 0; r < 4; r++) {
        float v = acc[mt][nt][r] * alpha;
        long idx = (crow + mt * 16 + r) * ldc + ccol + nt * 16;
        if (OUT_BF16)
          ((unsigned short*)Cout)[idx] = f2bf(v);
        else
          ((float*)Cout)[idx] = v;
      }
}

// ---------------- banded logits: att[b][n][m] = Q[n].K[m], 128x128 tiles ----------------
__global__ __launch_bounds__(256) void attn_logits(
    const unsigned short* __restrict__ Qb, const unsigned short* __restrict__ Kb,
    float* __restrict__ att) {
  int b = blockIdx.z;
  int n0 = blockIdx.y * 128;
  int m0 = n0 - 256 + blockIdx.x * 128;
  if (m0 + 128 <= 0 || m0 >= SEQ) return;
  __shared__ unsigned short sA[128 * 32];
  __shared__ unsigned short sB[128 * 32];
  const int K = 1024;
  int tid = threadIdx.x;
  int wid = tid >> 6, lane = tid & 63;
  int wr = wid >> 1, wc = wid & 1;

  floatx4 acc[4][4];
#pragma unroll
  for (int i = 0; i < 4; i++)
#pragma unroll
    for (int j = 0; j < 4; j++) acc[i][j] = (floatx4){0.f, 0.f, 0.f, 0.f};

  int c0 = wid * 64 + lane;
  int c1 = c0 + 256;
  const unsigned short* Qbase = Qb + (long)b * SEQ * K;
  const unsigned short* Kbase = Kb + (long)b * SEQ * K;
  int br0 = m0 + (c0 >> 2); br0 = br0 < 0 ? 0 : (br0 > SEQ - 1 ? SEQ - 1 : br0);
  int br1 = m0 + (c1 >> 2); br1 = br1 < 0 ? 0 : (br1 > SEQ - 1 ? SEQ - 1 : br1);
  const unsigned short* Ag0 = Qbase + (long)(n0 + (c0 >> 2)) * K + (c0 & 3) * 8;
  const unsigned short* Ag1 = Qbase + (long)(n0 + (c1 >> 2)) * K + (c1 & 3) * 8;
  const unsigned short* Bg0 = Kbase + (long)br0 * K + (c0 & 3) * 8;
  const unsigned short* Bg1 = Kbase + (long)br1 * K + (c1 & 3) * 8;
  unsigned short* sA0 = sA + (wid * 64) * 8;
  unsigned short* sA1 = sA + (256 + wid * 64) * 8;
  unsigned short* sB0 = sB + (wid * 64) * 8;
  unsigned short* sB1 = sB + (256 + wid * 64) * 8;

  int aRd = (wr * 64 + (lane & 15)) * 32 + (lane >> 4) * 8;
  int bRd = (wc * 64 + (lane & 15)) * 32 + (lane >> 4) * 8;

  for (int ks = 0; ks < K; ks += 32) {
    async16(Ag0 + ks, sA0);
    async16(Ag1 + ks, sA1);
    async16(Bg0 + ks, sB0);
    async16(Bg1 + ks, sB1);
    __syncthreads();
    short8 af[4], bf[4];
#pragma unroll
    for (int mt = 0; mt < 4; mt++) af[mt] = *(const short8*)(sA + aRd + mt * 512);
#pragma unroll
    for (int nt = 0; nt < 4; nt++) bf[nt] = *(const short8*)(sB + bRd + nt * 512);
#pragma unroll
    for (int mt = 0; mt < 4; mt++)
#pragma unroll
      for (int nt = 0; nt < 4; nt++)
        acc[mt][nt] = __builtin_amdgcn_mfma_f32_16x16x32_bf16(
            af[mt], bf[nt], acc[mt][nt], 0, 0, 0);
    __syncthreads();
  }

  float* attB = att + (long)b * SEQ * SEQ;
  int crow = n0 + wr * 64 + (lane >> 4) * 4;
  int ccol = m0 + wc * 64 + (lane & 15);
#pragma unroll
  for (int mt = 0; mt < 4; mt++)
#pragma unroll
    for (int nt = 0; nt < 4; nt++)
#pragma unroll
      for (int r = 0; r < 4; r++) {
        int row = crow + mt * 16 + r;
        int col = ccol + nt * 16;
        int d = row - col;
        if (col >= 0 && col < SEQ && d < 256 && d > -256)
          attB[(long)row * SEQ + col] = acc[mt][nt][r];
      }
}

// ---------------- softmax over band, 16 rows/block, LDS band cache ----------------
// attT2[b][nb][n&127][mi] = att[b][m = (nb*128)-256+mi][n], 640 mi slots
__global__ __launch_bounds__(256) void softmax_band(
    float* __restrict__ att, unsigned short* __restrict__ attT2) {
  __shared__ float e_lds[16 * 545];
  __shared__ float inv_s[16];
  int blk = blockIdx.x;          // 1024 blocks: 4 batches x 256 row-groups
  int b = blk >> 8;
  int r0 = (blk & 255) * 16;
  int tid = threadIdx.x;
  int row = tid >> 4;            // 0..15 within block
  int t16 = tid & 15;
  int i = r0 + row;
  int jbase = r0 - 272;
  float* arow = att + ((long)b * SEQ + i) * (long)SEQ;

  // phase 1a: load band window into regs, row max
  float raw[34];
  float m = -1e30f;
#pragma unroll
  for (int s = 0; s < 34; s++) {
    int jj = s * 16 + t16;
    int j = jbase + jj;
    bool ok = (j >= 0) && (j < SEQ) && (j >= i - 255) && (j <= i + 255);
    float v = ok ? arow[j] : -1e30f;
    raw[s] = v;
    m = fmaxf(m, v);
  }
#pragma unroll
  for (int off = 8; off; off >>= 1) m = fmaxf(m, __shfl_xor(m, off, 16));

  // phase 1b: exp, store to LDS, row sum
  float sum = 0.f;
#pragma unroll
  for (int s = 0; s < 34; s++) {
    int jj = s * 16 + t16;
    float e = (raw[s] > -1e29f) ? __expf(raw[s] - m) : 0.f;
    e_lds[row * 545 + jj] = e;
    sum += e;
  }
#pragma unroll
  for (int off = 8; off; off >>= 1) sum += __shfl_xor(sum, off, 16);
  float invr = 1.0f / sum;
  if (t16 == 0) inv_s[row] = invr;
  __syncthreads();

  // phase 1c: write full fp32 row (zeros outside band)
  for (int s = 0; s < 64; s++) {
    int j0 = (s * 16 + t16) * 4;
    float4 w;
    float* wp = (float*)&w;
#pragma unroll
    for (int k = 0; k < 4; k++) {
      int j = j0 + k;
      bool ok = (j >= i - 255) && (j <= i + 255);
      int jj = j - jbase;
      jj = jj < 0 ? 0 : (jj > 543 ? 543 : jj);
      wp[k] = ok ? e_lds[row * 545 + jj] * invr : 0.f;
    }
    *(float4*)(arow + j0) = w;
  }

  // phase 2: write attT2 (128-aligned band-compact transpose)
  int nn = tid >> 4;
  int mi16 = tid & 15;
  int i2 = r0 + mi16;
  float inv2 = inv_s[mi16];
  for (int s = 0; s <= 32; s++) {
    int n = r0 - 256 + s * 16 + nn;
    if (n < 0 || n >= SEQ) continue;
    int N0b = n & ~127;
    int mi = i2 - N0b + 256;
    if (mi < 0 || mi >= 640) continue;
    bool ok = (n >= i2 - 255) && (n <= i2 + 255);
    int jj = n - jbase;  // in [16, 543]
    float val = ok ? e_lds[mi16 * 545 + jj] * inv2 : 0.f;
    attT2[(((long)b * 32 + (N0b >> 7)) * 128 + (n & 127)) * 640 + mi] = f2bf(val);
  }
}

// ---------------- y[b][n][o] = sum_m att[b][m][n] * V[b][m][o] as 128x128 GEMM ----------------
// A = attT2[b][nb][128 n][640 mi], B = Vt[o][b*SEQ+m] (m contiguous), K=640
__global__ __launch_bounds__(256) void attv_gemm(
    const unsigned short* __restrict__ attT2, const unsigned short* __restrict__ Vt,
    unsigned short* __restrict__ yb) {
  __shared__ unsigned short sA[128 * 32];
  __shared__ unsigned short sB[128 * 32];
  const int KA = 640;
  int b = blockIdx.z;
  int tid = threadIdx.x;
  int wid = tid >> 6, lane = tid & 63;
  int wr = wid >> 1, wc = wid & 1;
  int N0 = blockIdx.x * 128;
  int o0 = blockIdx.y * 128;

  floatx4 acc[4][4];
#pragma unroll
  for (int i = 0; i < 4; i++)
#pragma unroll
    for (int j = 0; j < 4; j++) acc[i][j] = (floatx4){0.f, 0.f, 0.f, 0.f};

  int c0 = wid * 64 + lane;
  int c1 = c0 + 256;
  const unsigned short* Abase =
      attT2 + (((long)b * 32 + blockIdx.x) * 128) * KA;
  const unsigned short* Ag0 = Abase + (long)(c0 >> 2) * KA + (c0 & 3) * 8;
  const unsigned short* Ag1 = Abase + (long)(c1 >> 2) * KA + (c1 & 3) * 8;
  const unsigned short* Bg0 = Vt + (long)(o0 + (c0 >> 2)) * (NB * SEQ) + (c0 & 3) * 8;
  const unsigned short* Bg1 = Vt + (long)(o0 + (c1 >> 2)) * (NB * SEQ) + (c1 & 3) * 8;
  unsigned short* sA0 = sA + (wid * 64) * 8;
  unsigned short* sA1 = sA + (256 + wid * 64) * 8;
  unsigned short* sB0 = sB + (wid * 64) * 8;
  unsigned short* sB1 = sB + (256 + wid * 64) * 8;

  int aRd = (wr * 64 + (lane & 15)) * 32 + (lane >> 4) * 8;
  int bRd = (wc * 64 + (lane & 15)) * 32 + (lane >> 4) * 8;

  for (int ks = 0; ks < KA; ks += 32) {
    int mg = N0 - 256 + ks;
    int mc = mg < 0 ? 0 : (mg > SEQ - 32 ? SEQ - 32 : mg);
    long boff = (long)b * SEQ + mc;
    async16(Ag0 + ks, sA0);
    async16(Ag1 + ks, sA1);
    async16(Bg0 + boff, sB0);
    async16(Bg1 + boff, sB1);
    __syncthreads();
    short8 af[4], bf[4];
#pragma unroll
    for (int mt = 0; mt < 4; mt++) af[mt] = *(const short8*)(sA + aRd + mt * 512);
#pragma unroll
    for (int nt = 0; nt < 4; nt++) bf[nt] = *(const short8*)(sB + bRd + nt * 512);
#pragma unroll
    for (int mt = 0; mt < 4; mt++)
#pragma unroll
      for (int nt = 0; nt < 4; nt++)
        acc[mt][nt] = __builtin_amdgcn_mfma_f32_16x16x32_bf16(
            af[mt], bf[nt], acc[mt][nt], 0, 0, 0);
    __syncthreads();
  }

  long crow = (long)b * SEQ + N0 + wr * 64 + (lane >> 4) * 4;
  int ccol = o0 + wc * 64 + (lane & 15);
#pragma unroll
  for (int mt = 0; mt < 4; mt++)
#pragma unroll
    for (int nt = 0; nt < 4; nt++)
#pragma unroll
      for (int r = 0; r < 4; r++)
        yb[(crow + mt * 16 + r) * DM + ccol + nt * 16] = f2bf(acc[mt][nt][r]);
}

extern "C" void kernel_launch(void* const* d_in, const int* in_sizes, int n_in,
                              void* d_out, int out_size, void* d_ws, size_t ws_size,
                              hipStream_t stream) {
  const float* x  = (const float*)d_in[0];
  const float* Wk = (const float*)d_in[1];
  const float* Wq = (const float*)d_in[2];
  const float* Wv = (const float*)d_in[3];
  const float* Wo = (const float*)d_in[4];
  float* outY = (float*)d_out;
  float* outAtt = outY + (long)NB * SEQ * DM;

  char* ws = (char*)d_ws;
  unsigned short* xb  = (unsigned short*)(ws + 0);            // 32 MiB (reused as yb)
  unsigned short* Kb  = (unsigned short*)(ws + 33554432);     // 32 MiB (reused as attT2)
  unsigned short* Qb  = (unsigned short*)(ws + 67108864);     // 32 MiB
  unsigned short* Vt  = (unsigned short*)(ws + 100663296);    // 32 MiB  Vt[o][b*SEQ+m]
  unsigned short* Wkb = (unsigned short*)(ws + 134217728);
  unsigned short* Wqb = Wkb + 1048576;
  unsigned short* Wvb = Wqb + 1048576;
  unsigned short* Wob = Wvb + 1048576;
  unsigned short* attT2 = Kb;  // alias: Kb dead after attn_logits (21 MB)
  unsigned short* yb = xb;     // alias: xb dead after Q/K/Vt GEMMs

  cvt_bf16<<<8192, 256, 0, stream>>>(x, xb, NB * SEQ * DM);
  cvt_bf16<<<512, 256, 0, stream>>>(Wk, Wkb, DM * DM);
  cvt_bf16<<<512, 256, 0, stream>>>(Wq, Wqb, DM * DM);
  cvt_bf16<<<512, 256, 0, stream>>>(Wv, Wvb, DM * DM);
  cvt_bf16<<<512, 256, 0, stream>>>(Wo, Wob, DM * DM);

  // M=16384,N=1024 -> MT=64; M=1024,N=16384 (Vt) -> MT=4; grid always 256.
  gemm256<true, 64><<<256, 512, 0, stream>>>(xb, Wkb, Kb, 1.0f, 1024);
  gemm256<true, 64><<<256, 512, 0, stream>>>(xb, Wqb, Qb, QSCALE, 1024);
  gemm256<true, 4><<<256, 512, 0, stream>>>(Wvb, xb, Vt, 1.0f, NB * SEQ);

  attn_logits<<<dim3(5, 32, NB), 256, 0, stream>>>(Qb, Kb, outAtt);
  hipMemsetAsync(attT2, 0, (size_t)NB * 32 * 128 * 640 * 2, stream);
  softmax_band<<<1024, 256, 0, stream>>>(outAtt, attT2);
  attv_gemm<<<dim3(32, 8, NB), 256, 0, stream>>>(attT2, Vt, yb);
  gemm256<false, 64><<<256, 512, 0, stream>>>(yb, Wob, outY, 1.0f, 1024);
}

// Round 3
// 666.364 us; speedup vs baseline: 1.1046x; 1.0335x over previous
//
#include <hip/hip_runtime.h>
#include <stdint.h>

#define SEQ 4096
#define DM  1024
#define NB  4
#define QSCALE 0.06f

typedef __attribute__((ext_vector_type(8))) short short8;
typedef __attribute__((ext_vector_type(4))) float floatx4;

__device__ __forceinline__ unsigned short f2bf(float f) {
  union { float f; unsigned int u; } v; v.f = f;
  unsigned int u = v.u;
  u += 0x7FFFu + ((u >> 16) & 1u);
  return (unsigned short)(u >> 16);
}

__device__ __forceinline__ void async16(const void* g, void* l) {
  __builtin_amdgcn_global_load_lds(
      (const __attribute__((address_space(1))) void*)g,
      (__attribute__((address_space(3))) void*)l, 16, 0, 0);
}

// ---------------- fp32 -> bf16 convert (8 elems/thread) ----------------
__global__ void cvt_bf16(const float* __restrict__ in,
                         unsigned short* __restrict__ out, int n) {
  int i = (blockIdx.x * 256 + threadIdx.x) * 8;
  if (i >= n) return;
  const float4* p = (const float4*)(in + i);
  float4 a = p[0], b = p[1];
  short8 o;
  o[0] = (short)f2bf(a.x); o[1] = (short)f2bf(a.y);
  o[2] = (short)f2bf(a.z); o[3] = (short)f2bf(a.w);
  o[4] = (short)f2bf(b.x); o[5] = (short)f2bf(b.y);
  o[6] = (short)f2bf(b.z); o[7] = (short)f2bf(b.w);
  *(short8*)(out + i) = o;
}

// ---------------- 4 weight matrices -> one contiguous bf16 buffer ----------------
__global__ void cvt_w4(const float* __restrict__ wk, const float* __restrict__ wq,
                       const float* __restrict__ wv, const float* __restrict__ wo,
                       unsigned short* __restrict__ out) {
  int blk = blockIdx.x;            // 2048 = 4 x 512
  int sel = blk >> 9;
  const float* src = sel == 0 ? wk : sel == 1 ? wq : sel == 2 ? wv : wo;
  int i = ((blk & 511) * 256 + threadIdx.x) * 8;
  const float4* p = (const float4*)(src + i);
  float4 a = p[0], b = p[1];
  short8 o;
  o[0] = (short)f2bf(a.x); o[1] = (short)f2bf(a.y);
  o[2] = (short)f2bf(a.z); o[3] = (short)f2bf(a.w);
  o[4] = (short)f2bf(b.x); o[5] = (short)f2bf(b.y);
  o[6] = (short)f2bf(b.z); o[7] = (short)f2bf(b.w);
  *(short8*)(out + sel * 1048576 + i) = o;
}

// ---------------- 256x256 bf16 GEMM, C = A * W^T, K=1024 ----------------
// 8 waves (2Mx4N), BK=32, 4 LDS buffers (128 KiB), prefetch depth 3,
// counted vmcnt(8) at K-tile boundaries, raw s_barrier + s_setprio.
// DUAL mode: W is a [NT*256/..] stacked weight (K rows then Q rows);
// by < NT/2 writes C0 (alpha a0), else C1 (alpha a1) at col - NT/2*256.
template <bool OUT_BF16, int MT, int NT, bool DUAL>
__global__ __launch_bounds__(512, 2) void gemm256(
    const unsigned short* __restrict__ A, const unsigned short* __restrict__ W,
    void* __restrict__ C0, void* __restrict__ C1, float a0, float a1, long ldc) {
  __shared__ __align__(16) unsigned short lds[4 * 16384];
  const int K = 1024;
  const int NKT = 32;  // K / 32
  int tid = threadIdx.x;
  int lane = tid & 63;
  int wid = tid >> 6;
  int wr = wid >> 2, wc = wid & 3;

  // bijective XCD swizzle, nwg = MT*NT (divisible by 8)
  const int CPX = (MT * NT) >> 3;
  int bid = blockIdx.x;
  int raw = (bid & 7) * CPX + (bid >> 3);
  int bx = raw % MT;
  int by = raw / MT;
  long brow = (long)bx * 256;
  long bcol = (long)by * 256;

  floatx4 acc[8][4];
#pragma unroll
  for (int i = 0; i < 8; i++)
#pragma unroll
    for (int j = 0; j < 4; j++) acc[i][j] = (floatx4){0.f, 0.f, 0.f, 0.f};

  const unsigned short* Ag = A + (brow + (tid >> 2)) * K + (tid & 3) * 8;
  const unsigned short* Wg = W + (bcol + (tid >> 2)) * K + (tid & 3) * 8;
  unsigned short* ldsW = lds + wid * 512;  // wave-uniform LDS dest base

  int aRd = (wr * 128 + (lane & 15)) * 32 + (lane >> 4) * 8;
  int bRd = (wc * 64 + (lane & 15)) * 32 + (lane >> 4) * 8;

#pragma unroll
  for (int tt = 0; tt < 3; tt++) {
    unsigned short* d = ldsW + tt * 16384;
    const unsigned short* a = Ag + tt * 32;
    const unsigned short* w = Wg + tt * 32;
    async16(a, d);
    async16(a + 128 * K, d + 4096);
    async16(w, d + 8192);
    async16(w + 128 * K, d + 12288);
  }
  asm volatile("s_waitcnt vmcnt(8)" ::: "memory");
  __builtin_amdgcn_s_barrier();

  for (int t = 0; t < NKT; ++t) {
    const unsigned short* bufA = lds + (t & 3) * 16384;
    const unsigned short* bufB = bufA + 8192;
    short8 a0f[4], b0f[4], a1f[4];
#pragma unroll
    for (int mt = 0; mt < 4; mt++)
      a0f[mt] = *(const short8*)(bufA + aRd + mt * 512);
#pragma unroll
    for (int nt = 0; nt < 4; nt++)
      b0f[nt] = *(const short8*)(bufB + bRd + nt * 512);
    if (t + 3 < NKT) {
      unsigned short* d = ldsW + ((t + 3) & 3) * 16384;
      const unsigned short* a = Ag + (t + 3) * 32;
      async16(a, d);
      async16(a + 128 * K, d + 4096);
    }
    __builtin_amdgcn_s_barrier();
    __builtin_amdgcn_s_setprio(1);
#pragma unroll
    for (int mt = 0; mt < 4; mt++)
#pragma unroll
      for (int nt = 0; nt < 4; nt++)
        acc[mt][nt] = __builtin_amdgcn_mfma_f32_16x16x32_bf16(
            a0f[mt], b0f[nt], acc[mt][nt], 0, 0, 0);
    __builtin_amdgcn_s_setprio(0);
    __builtin_amdgcn_s_barrier();
#pragma unroll
    for (int mt = 0; mt < 4; mt++)
      a1f[mt] = *(const short8*)(bufA + aRd + 2048 + mt * 512);
    if (t + 3 < NKT) {
      unsigned short* d = ldsW + ((t + 3) & 3) * 16384;
      const unsigned short* w = Wg + (t + 3) * 32;
      async16(w, d + 8192);
      async16(w + 128 * K, d + 12288);
    }
    __builtin_amdgcn_s_barrier();
    __builtin_amdgcn_s_setprio(1);
#pragma unroll
    for (int mt = 0; mt < 4; mt++)
#pragma unroll
      for (int nt = 0; nt < 4; nt++)
        acc[4 + mt][nt] = __builtin_amdgcn_mfma_f32_16x16x32_bf16(
            a1f[mt], b0f[nt], acc[4 + mt][nt], 0, 0, 0);
    __builtin_amdgcn_s_setprio(0);
    if (t < NKT - 3)
      asm volatile("s_waitcnt vmcnt(8)" ::: "memory");
    else if (t == NKT - 3)
      asm volatile("s_waitcnt vmcnt(4)" ::: "memory");
    else
      asm volatile("s_waitcnt vmcnt(0)" ::: "memory");
    __builtin_amdgcn_s_barrier();
  }

  void* Cp;
  float alpha;
  long cc;
  if (DUAL && by >= NT / 2) {
    Cp = C1; alpha = a1; cc = bcol - (long)(NT / 2) * 256;
  } else {
    Cp = C0; alpha = a0; cc = bcol;
  }
  long crow = brow + wr * 128 + (lane >> 4) * 4;
  long ccol = cc + wc * 64 + (lane & 15);
#pragma unroll
  for (int mt = 0; mt < 8; mt++)
#pragma unroll
    for (int nt = 0; nt < 4; nt++)
#pragma unroll
      for (int r = 0; r < 4; r++) {
        float v = acc[mt][nt][r] * alpha;
        long idx = (crow + mt * 16 + r) * ldc + ccol + nt * 16;
        if (OUT_BF16)
          ((unsigned short*)Cp)[idx] = f2bf(v);
        else
          ((float*)Cp)[idx] = v;
      }
}

// ---------------- banded logits: att[b][n][m] = Q[n].K[m], 128x128 tiles ----------------
__global__ __launch_bounds__(256) void attn_logits(
    const unsigned short* __restrict__ Qb, const unsigned short* __restrict__ Kb,
    float* __restrict__ att) {
  int b = blockIdx.z;
  int n0 = blockIdx.y * 128;
  int m0 = n0 - 256 + blockIdx.x * 128;
  if (m0 + 128 <= 0 || m0 >= SEQ) return;
  __shared__ unsigned short sA[128 * 32];
  __shared__ unsigned short sB[128 * 32];
  const int K = 1024;
  int tid = threadIdx.x;
  int wid = tid >> 6, lane = tid & 63;
  int wr = wid >> 1, wc = wid & 1;

  floatx4 acc[4][4];
#pragma unroll
  for (int i = 0; i < 4; i++)
#pragma unroll
    for (int j = 0; j < 4; j++) acc[i][j] = (floatx4){0.f, 0.f, 0.f, 0.f};

  int c0 = wid * 64 + lane;
  int c1 = c0 + 256;
  const unsigned short* Qbase = Qb + (long)b * SEQ * K;
  const unsigned short* Kbase = Kb + (long)b * SEQ * K;
  int br0 = m0 + (c0 >> 2); br0 = br0 < 0 ? 0 : (br0 > SEQ - 1 ? SEQ - 1 : br0);
  int br1 = m0 + (c1 >> 2); br1 = br1 < 0 ? 0 : (br1 > SEQ - 1 ? SEQ - 1 : br1);
  const unsigned short* Ag0 = Qbase + (long)(n0 + (c0 >> 2)) * K + (c0 & 3) * 8;
  const unsigned short* Ag1 = Qbase + (long)(n0 + (c1 >> 2)) * K + (c1 & 3) * 8;
  const unsigned short* Bg0 = Kbase + (long)br0 * K + (c0 & 3) * 8;
  const unsigned short* Bg1 = Kbase + (long)br1 * K + (c1 & 3) * 8;
  unsigned short* sA0 = sA + (wid * 64) * 8;
  unsigned short* sA1 = sA + (256 + wid * 64) * 8;
  unsigned short* sB0 = sB + (wid * 64) * 8;
  unsigned short* sB1 = sB + (256 + wid * 64) * 8;

  int aRd = (wr * 64 + (lane & 15)) * 32 + (lane >> 4) * 8;
  int bRd = (wc * 64 + (lane & 15)) * 32 + (lane >> 4) * 8;

  for (int ks = 0; ks < K; ks += 32) {
    async16(Ag0 + ks, sA0);
    async16(Ag1 + ks, sA1);
    async16(Bg0 + ks, sB0);
    async16(Bg1 + ks, sB1);
    __syncthreads();
    short8 af[4], bf[4];
#pragma unroll
    for (int mt = 0; mt < 4; mt++) af[mt] = *(const short8*)(sA + aRd + mt * 512);
#pragma unroll
    for (int nt = 0; nt < 4; nt++) bf[nt] = *(const short8*)(sB + bRd + nt * 512);
#pragma unroll
    for (int mt = 0; mt < 4; mt++)
#pragma unroll
      for (int nt = 0; nt < 4; nt++)
        acc[mt][nt] = __builtin_amdgcn_mfma_f32_16x16x32_bf16(
            af[mt], bf[nt], acc[mt][nt], 0, 0, 0);
    __syncthreads();
  }

  float* attB = att + (long)b * SEQ * SEQ;
  int crow = n0 + wr * 64 + (lane >> 4) * 4;
  int ccol = m0 + wc * 64 + (lane & 15);
#pragma unroll
  for (int mt = 0; mt < 4; mt++)
#pragma unroll
    for (int nt = 0; nt < 4; nt++)
#pragma unroll
      for (int r = 0; r < 4; r++) {
        int row = crow + mt * 16 + r;
        int col = ccol + nt * 16;
        int d = row - col;
        if (col >= 0 && col < SEQ && d < 256 && d > -256)
          attB[(long)row * SEQ + col] = acc[mt][nt][r];
      }
}

// ---------------- softmax over band, 16 rows/block, LDS band cache ----------------
// attT2[b][nb2][n&255][mi] = att[b][m = (nb2*256)-256+mi][n], 768 mi slots
__global__ __launch_bounds__(256) void softmax_band(
    float* __restrict__ att, unsigned short* __restrict__ attT2) {
  __shared__ float e_lds[16 * 545];
  __shared__ float inv_s[16];
  int blk = blockIdx.x;          // 1024 blocks: 4 batches x 256 row-groups
  int b = blk >> 8;
  int r0 = (blk & 255) * 16;
  int tid = threadIdx.x;
  int row = tid >> 4;            // 0..15 within block
  int t16 = tid & 15;
  int i = r0 + row;
  int jbase = r0 - 272;
  float* arow = att + ((long)b * SEQ + i) * (long)SEQ;

  // phase 1a: load band window into regs, row max
  float raw[34];
  float m = -1e30f;
#pragma unroll
  for (int s = 0; s < 34; s++) {
    int jj = s * 16 + t16;
    int j = jbase + jj;
    bool ok = (j >= 0) && (j < SEQ) && (j >= i - 255) && (j <= i + 255);
    float v = ok ? arow[j] : -1e30f;
    raw[s] = v;
    m = fmaxf(m, v);
  }
#pragma unroll
  for (int off = 8; off; off >>= 1) m = fmaxf(m, __shfl_xor(m, off, 16));

  // phase 1b: exp, store to LDS, row sum
  float sum = 0.f;
#pragma unroll
  for (int s = 0; s < 34; s++) {
    int jj = s * 16 + t16;
    float e = (raw[s] > -1e29f) ? __expf(raw[s] - m) : 0.f;
    e_lds[row * 545 + jj] = e;
    sum += e;
  }
#pragma unroll
  for (int off = 8; off; off >>= 1) sum += __shfl_xor(sum, off, 16);
  float invr = 1.0f / sum;
  if (t16 == 0) inv_s[row] = invr;
  __syncthreads();

  // phase 1c: write full fp32 row (zeros outside band)
  for (int s = 0; s < 64; s++) {
    int j0 = (s * 16 + t16) * 4;
    float4 w;
    float* wp = (float*)&w;
#pragma unroll
    for (int k = 0; k < 4; k++) {
      int j = j0 + k;
      bool ok = (j >= i - 255) && (j <= i + 255);
      int jj = j - jbase;
      jj = jj < 0 ? 0 : (jj > 543 ? 543 : jj);
      wp[k] = ok ? e_lds[row * 545 + jj] * invr : 0.f;
    }
    *(float4*)(arow + j0) = w;
  }

  // phase 2: write attT2 (256-aligned band-compact transpose, 768-wide window)
  // thread owns m-row i2 = r0 + (tid&15); iterates n over [Bc-256, Bc+512)
  int nn = tid >> 4;
  int mi16 = tid & 15;
  int i2 = r0 + mi16;
  float inv2 = inv_s[mi16];
  int Bc = r0 & ~255;            // uniform: [r0, r0+16) never crosses a 256-boundary
  for (int s = 0; s < 48; s++) {
    int n = Bc - 256 + s * 16 + nn;
    if (n < 0 || n >= SEQ) continue;
    int mi = i2 - (n & ~255) + 256;  // always in [0,768)
    bool ok = (n >= i2 - 255) && (n <= i2 + 255);
    int jj = n - jbase;
    jj = jj < 0 ? 0 : (jj > 544 ? 544 : jj);
    float val = ok ? e_lds[mi16 * 545 + jj] * inv2 : 0.f;
    attT2[(((long)b * 16 + (n >> 8)) * 256 + (n & 255)) * 768 + mi] = f2bf(val);
  }
}

// ---------------- y[b][n][o] = sum_m att[b][m][n] * V[b][m][o], 256x256 pipelined ----------------
// A = attT2[b][nb2][256 n][768 mi], B = Vt[o][b*SEQ+m] (m contiguous), K=768
__global__ __launch_bounds__(512, 2) void attv256(
    const unsigned short* __restrict__ attT2, const unsigned short* __restrict__ Vt,
    unsigned short* __restrict__ yb) {
  __shared__ __align__(16) unsigned short lds[4 * 16384];
  const int KA = 768;
  const int NKT = 24;
  int b = blockIdx.z;
  int nb2 = blockIdx.x;        // 16
  int o0 = blockIdx.y * 256;   // 4
  int N0 = nb2 * 256;
  int tid = threadIdx.x;
  int lane = tid & 63;
  int wid = tid >> 6;
  int wr = wid >> 2, wc = wid & 3;

  floatx4 acc[8][4];
#pragma unroll
  for (int i = 0; i < 8; i++)
#pragma unroll
    for (int j = 0; j < 4; j++) acc[i][j] = (floatx4){0.f, 0.f, 0.f, 0.f};

  const unsigned short* Abase = attT2 + ((long)(b * 16 + nb2) * 256) * KA;
  const unsigned short* Ag = Abase + (long)(tid >> 2) * KA + (tid & 3) * 8;
  const unsigned short* Vg =
      Vt + (long)(o0 + (tid >> 2)) * (NB * SEQ) + (tid & 3) * 8;
  unsigned short* ldsW = lds + wid * 512;

  int aRd = (wr * 128 + (lane & 15)) * 32 + (lane >> 4) * 8;
  int bRd = (wc * 64 + (lane & 15)) * 32 + (lane >> 4) * 8;

  // per-tile B k-offset: m chunk clamped (A is zero on phantom mi slots)
  auto boff = [&](int t) {
    int mg = N0 - 256 + t * 32;
    int mc = mg < 0 ? 0 : (mg > SEQ - 32 ? SEQ - 32 : mg);
    return (long)b * SEQ + mc;
  };

#pragma unroll
  for (int tt = 0; tt < 3; tt++) {
    unsigned short* d = ldsW + tt * 16384;
    async16(Ag + tt * 32, d);
    async16(Ag + 128 * KA + tt * 32, d + 4096);
    long bo = boff(tt);
    async16(Vg + bo, d + 8192);
    async16(Vg + 128L * (NB * SEQ) + bo, d + 12288);
  }
  asm volatile("s_waitcnt vmcnt(8)" ::: "memory");
  __builtin_amdgcn_s_barrier();

  for (int t = 0; t < NKT; ++t) {
    const unsigned short* bufA = lds + (t & 3) * 16384;
    const unsigned short* bufB = bufA + 8192;
    short8 a0f[4], b0f[4], a1f[4];
#pragma unroll
    for (int mt = 0; mt < 4; mt++)
      a0f[mt] = *(const short8*)(bufA + aRd + mt * 512);
#pragma unroll
    for (int nt = 0; nt < 4; nt++)
      b0f[nt] = *(const short8*)(bufB + bRd + nt * 512);
    if (t + 3 < NKT) {
      unsigned short* d = ldsW + ((t + 3) & 3) * 16384;
      async16(Ag + (t + 3) * 32, d);
      async16(Ag + 128 * KA + (t + 3) * 32, d + 4096);
    }
    __builtin_amdgcn_s_barrier();
    __builtin_amdgcn_s_setprio(1);
#pragma unroll
    for (int mt = 0; mt < 4; mt++)
#pragma unroll
      for (int nt = 0; nt < 4; nt++)
        acc[mt][nt] = __builtin_amdgcn_mfma_f32_16x16x32_bf16(
            a0f[mt], b0f[nt], acc[mt][nt], 0, 0, 0);
    __builtin_amdgcn_s_setprio(0);
    __builtin_amdgcn_s_barrier();
#pragma unroll
    for (int mt = 0; mt < 4; mt++)
      a1f[mt] = *(const short8*)(bufA + aRd + 2048 + mt * 512);
    if (t + 3 < NKT) {
      unsigned short* d = ldsW + ((t + 3) & 3) * 16384;
      long bo = boff(t + 3);
      async16(Vg + bo, d + 8192);
      async16(Vg + 128L * (NB * SEQ) + bo, d + 12288);
    }
    __builtin_amdgcn_s_barrier();
    __builtin_amdgcn_s_setprio(1);
#pragma unroll
    for (int mt = 0; mt < 4; mt++)
#pragma unroll
      for (int nt = 0; nt < 4; nt++)
        acc[4 + mt][nt] = __builtin_amdgcn_mfma_f32_16x16x32_bf16(
            a1f[mt], b0f[nt], acc[4 + mt][nt], 0, 0, 0);
    __builtin_amdgcn_s_setprio(0);
    if (t < NKT - 3)
      asm volatile("s_waitcnt vmcnt(8)" ::: "memory");
    else if (t == NKT - 3)
      asm volatile("s_waitcnt vmcnt(4)" ::: "memory");
    else
      asm volatile("s_waitcnt vmcnt(0)" ::: "memory");
    __builtin_amdgcn_s_barrier();
  }

  long crow = (long)b * SEQ + N0 + wr * 128 + (lane >> 4) * 4;
  int ccol = o0 + wc * 64 + (lane & 15);
#pragma unroll
  for (int mt = 0; mt < 8; mt++)
#pragma unroll
    for (int nt = 0; nt < 4; nt++)
#pragma unroll
      for (int r = 0; r < 4; r++)
        yb[(crow + mt * 16 + r) * DM + ccol + nt * 16] = f2bf(acc[mt][nt][r]);
}

extern "C" void kernel_launch(void* const* d_in, const int* in_sizes, int n_in,
                              void* d_out, int out_size, void* d_ws, size_t ws_size,
                              hipStream_t stream) {
  const float* x  = (const float*)d_in[0];
  const float* Wk = (const float*)d_in[1];
  const float* Wq = (const float*)d_in[2];
  const float* Wv = (const float*)d_in[3];
  const float* Wo = (const float*)d_in[4];
  float* outY = (float*)d_out;
  float* outAtt = outY + (long)NB * SEQ * DM;

  char* ws = (char*)d_ws;
  unsigned short* xb  = (unsigned short*)(ws + 0);            // 32 MiB (reused as yb)
  unsigned short* Kb  = (unsigned short*)(ws + 33554432);     // 32 MiB (reused as attT2)
  unsigned short* Qb  = (unsigned short*)(ws + 67108864);     // 32 MiB
  unsigned short* Vt  = (unsigned short*)(ws + 100663296);    // 32 MiB  Vt[o][b*SEQ+m]
  unsigned short* Wkb = (unsigned short*)(ws + 134217728);    // K,Q,V,O contiguous (8 MiB)
  unsigned short* Wvb = Wkb + 2097152;
  unsigned short* Wob = Wvb + 1048576;
  unsigned short* attT2 = Kb;  // alias: Kb dead after attn_logits (25.2 MB as 768-window)
  unsigned short* yb = xb;     // alias: xb dead after Q/K/Vt GEMMs

  cvt_bf16<<<8192, 256, 0, stream>>>(x, xb, NB * SEQ * DM);
  cvt_w4<<<2048, 256, 0, stream>>>(Wk, Wq, Wv, Wo, Wkb);

  // fused K+Q: W = [Wk;Wq] (2048x1024), grid 512 = 2 blocks/CU
  gemm256<true, 64, 8, true><<<512, 512, 0, stream>>>(
      xb, Wkb, Kb, Qb, 1.0f, QSCALE, 1024);
  // Vt = Wv * xb^T  (M=1024 -> MT=4, N=16384 -> NT=64)
  gemm256<true, 4, 64, false><<<256, 512, 0, stream>>>(
      Wvb, xb, Vt, nullptr, 1.0f, 1.0f, NB * SEQ);

  attn_logits<<<dim3(5, 32, NB), 256, 0, stream>>>(Qb, Kb, outAtt);
  hipMemsetAsync(attT2, 0, (size_t)NB * 16 * 256 * 768 * 2, stream);
  softmax_band<<<1024, 256, 0, stream>>>(outAtt, attT2);
  attv256<<<dim3(16, 4, NB), 512, 0, stream>>>(attT2, Vt, yb);
  gemm256<false, 64, 4, false><<<256, 512, 0, stream>>>(
      yb, Wob, outY, nullptr, 1.0f, 1.0f, 1024);
}

// Round 4
// 640.037 us; speedup vs baseline: 1.1500x; 1.0411x over previous
//
#include <hip/hip_runtime.h>
#include <stdint.h>

#define SEQ 4096
#define DM  1024
#define NB  4
#define QSCALE 0.06f

typedef __attribute__((ext_vector_type(8))) short short8;
typedef __attribute__((ext_vector_type(4))) float floatx4;

__device__ __forceinline__ unsigned short f2bf(float f) {
  union { float f; unsigned int u; } v; v.f = f;
  unsigned int u = v.u;
  u += 0x7FFFu + ((u >> 16) & 1u);
  return (unsigned short)(u >> 16);
}

__device__ __forceinline__ void async16(const void* g, void* l) {
  __builtin_amdgcn_global_load_lds(
      (const __attribute__((address_space(1))) void*)g,
      (__attribute__((address_space(3))) void*)l, 16, 0, 0);
}

// ---------------- fp32 -> bf16 convert: x (8192 blks) + 4 weights (2048 blks) ----------------
__global__ void cvt_all(const float* __restrict__ x, const float* __restrict__ wk,
                        const float* __restrict__ wq, const float* __restrict__ wv,
                        const float* __restrict__ wo, unsigned short* __restrict__ xb,
                        unsigned short* __restrict__ wb) {
  int blk = blockIdx.x;
  const float* src;
  unsigned short* dst;
  int i;
  if (blk < 8192) {
    src = x; dst = xb; i = (blk * 256 + threadIdx.x) * 8;
  } else {
    int w = blk - 8192;
    int sel = w >> 9;
    src = sel == 0 ? wk : sel == 1 ? wq : sel == 2 ? wv : wo;
    dst = wb + sel * 1048576;
    i = ((w & 511) * 256 + threadIdx.x) * 8;
  }
  const float4* p = (const float4*)(src + i);
  float4 a = p[0], b = p[1];
  short8 o;
  o[0] = (short)f2bf(a.x); o[1] = (short)f2bf(a.y);
  o[2] = (short)f2bf(a.z); o[3] = (short)f2bf(a.w);
  o[4] = (short)f2bf(b.x); o[5] = (short)f2bf(b.y);
  o[6] = (short)f2bf(b.z); o[7] = (short)f2bf(b.w);
  *(short8*)(dst + i) = o;
}

// ---------------- 256x256 bf16 GEMM, C = A * W^T, K=1024 ----------------
// 8 waves (2Mx4N), BK=32, 4 LDS buffers (128 KiB), prefetch depth 3,
// counted vmcnt(8) at K-tile boundaries, raw s_barrier + s_setprio.
// DUAL mode: W is a stacked [2048x1024] weight; by >= NT/2 writes C1.
template <bool OUT_BF16, int MT, int NT, bool DUAL>
__global__ __launch_bounds__(512, 2) void gemm256(
    const unsigned short* __restrict__ A, const unsigned short* __restrict__ W,
    void* __restrict__ C0, void* __restrict__ C1, float a0, float a1, long ldc) {
  __shared__ __align__(16) unsigned short lds[4 * 16384];
  const int K = 1024;
  const int NKT = 32;  // K / 32
  int tid = threadIdx.x;
  int lane = tid & 63;
  int wid = tid >> 6;
  int wr = wid >> 2, wc = wid & 3;

  // bijective XCD swizzle, nwg = MT*NT (divisible by 8)
  const int CPX = (MT * NT) >> 3;
  int bid = blockIdx.x;
  int raw = (bid & 7) * CPX + (bid >> 3);
  int bx = raw % MT;
  int by = raw / MT;
  long brow = (long)bx * 256;
  long bcol = (long)by * 256;

  floatx4 acc[8][4];
#pragma unroll
  for (int i = 0; i < 8; i++)
#pragma unroll
    for (int j = 0; j < 4; j++) acc[i][j] = (floatx4){0.f, 0.f, 0.f, 0.f};

  const unsigned short* Ag = A + (brow + (tid >> 2)) * K + (tid & 3) * 8;
  const unsigned short* Wg = W + (bcol + (tid >> 2)) * K + (tid & 3) * 8;
  unsigned short* ldsW = lds + wid * 512;  // wave-uniform LDS dest base

  int aRd = (wr * 128 + (lane & 15)) * 32 + (lane >> 4) * 8;
  int bRd = (wc * 64 + (lane & 15)) * 32 + (lane >> 4) * 8;

#pragma unroll
  for (int tt = 0; tt < 3; tt++) {
    unsigned short* d = ldsW + tt * 16384;
    const unsigned short* a = Ag + tt * 32;
    const unsigned short* w = Wg + tt * 32;
    async16(a, d);
    async16(a + 128 * K, d + 4096);
    async16(w, d + 8192);
    async16(w + 128 * K, d + 12288);
  }
  asm volatile("s_waitcnt vmcnt(8)" ::: "memory");
  __builtin_amdgcn_s_barrier();

  for (int t = 0; t < NKT; ++t) {
    const unsigned short* bufA = lds + (t & 3) * 16384;
    const unsigned short* bufB = bufA + 8192;
    short8 a0f[4], b0f[4], a1f[4];
#pragma unroll
    for (int mt = 0; mt < 4; mt++)
      a0f[mt] = *(const short8*)(bufA + aRd + mt * 512);
#pragma unroll
    for (int nt = 0; nt < 4; nt++)
      b0f[nt] = *(const short8*)(bufB + bRd + nt * 512);
    if (t + 3 < NKT) {
      unsigned short* d = ldsW + ((t + 3) & 3) * 16384;
      const unsigned short* a = Ag + (t + 3) * 32;
      async16(a, d);
      async16(a + 128 * K, d + 4096);
    }
    __builtin_amdgcn_s_barrier();
    __builtin_amdgcn_s_setprio(1);
#pragma unroll
    for (int mt = 0; mt < 4; mt++)
#pragma unroll
      for (int nt = 0; nt < 4; nt++)
        acc[mt][nt] = __builtin_amdgcn_mfma_f32_16x16x32_bf16(
            a0f[mt], b0f[nt], acc[mt][nt], 0, 0, 0);
    __builtin_amdgcn_s_setprio(0);
    __builtin_amdgcn_s_barrier();
#pragma unroll
    for (int mt = 0; mt < 4; mt++)
      a1f[mt] = *(const short8*)(bufA + aRd + 2048 + mt * 512);
    if (t + 3 < NKT) {
      unsigned short* d = ldsW + ((t + 3) & 3) * 16384;
      const unsigned short* w = Wg + (t + 3) * 32;
      async16(w, d + 8192);
      async16(w + 128 * K, d + 12288);
    }
    __builtin_amdgcn_s_barrier();
    __builtin_amdgcn_s_setprio(1);
#pragma unroll
    for (int mt = 0; mt < 4; mt++)
#pragma unroll
      for (int nt = 0; nt < 4; nt++)
        acc[4 + mt][nt] = __builtin_amdgcn_mfma_f32_16x16x32_bf16(
            a1f[mt], b0f[nt], acc[4 + mt][nt], 0, 0, 0);
    __builtin_amdgcn_s_setprio(0);
    if (t < NKT - 3)
      asm volatile("s_waitcnt vmcnt(8)" ::: "memory");
    else if (t == NKT - 3)
      asm volatile("s_waitcnt vmcnt(4)" ::: "memory");
    else
      asm volatile("s_waitcnt vmcnt(0)" ::: "memory");
    __builtin_amdgcn_s_barrier();
  }

  void* Cp;
  float alpha;
  long cc;
  if (DUAL && by >= NT / 2) {
    Cp = C1; alpha = a1; cc = bcol - (long)(NT / 2) * 256;
  } else {
    Cp = C0; alpha = a0; cc = bcol;
  }
  long crow = brow + wr * 128 + (lane >> 4) * 4;
  long ccol = cc + wc * 64 + (lane & 15);
#pragma unroll
  for (int mt = 0; mt < 8; mt++)
#pragma unroll
    for (int nt = 0; nt < 4; nt++)
#pragma unroll
      for (int r = 0; r < 4; r++) {
        float v = acc[mt][nt][r] * alpha;
        long idx = (crow + mt * 16 + r) * ldc + ccol + nt * 16;
        if (OUT_BF16)
          ((unsigned short*)Cp)[idx] = f2bf(v);
        else
          ((float*)Cp)[idx] = v;
      }
}

// ---------------- banded logits via the same 256x256 pipeline ----------------
// grid (16 n-tiles, 3 m-offsets {-256,0,+256}, NB); fp32 band-masked epilogue.
// Per-output accumulation order identical to the old kernel (ascending BK=32).
__global__ __launch_bounds__(512, 2) void logits256(
    const unsigned short* __restrict__ Qb, const unsigned short* __restrict__ Kb,
    float* __restrict__ att) {
  int b = blockIdx.z;
  int n0 = blockIdx.x * 256;
  int m0 = n0 + ((int)blockIdx.y - 1) * 256;
  if (m0 < 0 || m0 >= SEQ) return;
  __shared__ __align__(16) unsigned short lds[4 * 16384];
  const int K = 1024;
  const int NKT = 32;
  int tid = threadIdx.x;
  int lane = tid & 63;
  int wid = tid >> 6;
  int wr = wid >> 2, wc = wid & 3;

  floatx4 acc[8][4];
#pragma unroll
  for (int i = 0; i < 8; i++)
#pragma unroll
    for (int j = 0; j < 4; j++) acc[i][j] = (floatx4){0.f, 0.f, 0.f, 0.f};

  const unsigned short* Ag =
      Qb + ((long)b * SEQ + n0 + (tid >> 2)) * K + (tid & 3) * 8;
  const unsigned short* Wg =
      Kb + ((long)b * SEQ + m0 + (tid >> 2)) * K + (tid & 3) * 8;
  unsigned short* ldsW = lds + wid * 512;

  int aRd = (wr * 128 + (lane & 15)) * 32 + (lane >> 4) * 8;
  int bRd = (wc * 64 + (lane & 15)) * 32 + (lane >> 4) * 8;

#pragma unroll
  for (int tt = 0; tt < 3; tt++) {
    unsigned short* d = ldsW + tt * 16384;
    const unsigned short* a = Ag + tt * 32;
    const unsigned short* w = Wg + tt * 32;
    async16(a, d);
    async16(a + 128 * K, d + 4096);
    async16(w, d + 8192);
    async16(w + 128 * K, d + 12288);
  }
  asm volatile("s_waitcnt vmcnt(8)" ::: "memory");
  __builtin_amdgcn_s_barrier();

  for (int t = 0; t < NKT; ++t) {
    const unsigned short* bufA = lds + (t & 3) * 16384;
    const unsigned short* bufB = bufA + 8192;
    short8 a0f[4], b0f[4], a1f[4];
#pragma unroll
    for (int mt = 0; mt < 4; mt++)
      a0f[mt] = *(const short8*)(bufA + aRd + mt * 512);
#pragma unroll
    for (int nt = 0; nt < 4; nt++)
      b0f[nt] = *(const short8*)(bufB + bRd + nt * 512);
    if (t + 3 < NKT) {
      unsigned short* d = ldsW + ((t + 3) & 3) * 16384;
      const unsigned short* a = Ag + (t + 3) * 32;
      async16(a, d);
      async16(a + 128 * K, d + 4096);
    }
    __builtin_amdgcn_s_barrier();
    __builtin_amdgcn_s_setprio(1);
#pragma unroll
    for (int mt = 0; mt < 4; mt++)
#pragma unroll
      for (int nt = 0; nt < 4; nt++)
        acc[mt][nt] = __builtin_amdgcn_mfma_f32_16x16x32_bf16(
            a0f[mt], b0f[nt], acc[mt][nt], 0, 0, 0);
    __builtin_amdgcn_s_setprio(0);
    __builtin_amdgcn_s_barrier();
#pragma unroll
    for (int mt = 0; mt < 4; mt++)
      a1f[mt] = *(const short8*)(bufA + aRd + 2048 + mt * 512);
    if (t + 3 < NKT) {
      unsigned short* d = ldsW + ((t + 3) & 3) * 16384;
      const unsigned short* w = Wg + (t + 3) * 32;
      async16(w, d + 8192);
      async16(w + 128 * K, d + 12288);
    }
    __builtin_amdgcn_s_barrier();
    __builtin_amdgcn_s_setprio(1);
#pragma unroll
    for (int mt = 0; mt < 4; mt++)
#pragma unroll
      for (int nt = 0; nt < 4; nt++)
        acc[4 + mt][nt] = __builtin_amdgcn_mfma_f32_16x16x32_bf16(
            a1f[mt], b0f[nt], acc[4 + mt][nt], 0, 0, 0);
    __builtin_amdgcn_s_setprio(0);
    if (t < NKT - 3)
      asm volatile("s_waitcnt vmcnt(8)" ::: "memory");
    else if (t == NKT - 3)
      asm volatile("s_waitcnt vmcnt(4)" ::: "memory");
    else
      asm volatile("s_waitcnt vmcnt(0)" ::: "memory");
    __builtin_amdgcn_s_barrier();
  }

  float* attB = att + (long)b * SEQ * SEQ;
  int crow = n0 + wr * 128 + (lane >> 4) * 4;
  int ccol = m0 + wc * 64 + (lane & 15);
#pragma unroll
  for (int mt = 0; mt < 8; mt++)
#pragma unroll
    for (int nt = 0; nt < 4; nt++)
#pragma unroll
      for (int r = 0; r < 4; r++) {
        int row = crow + mt * 16 + r;
        int col = ccol + nt * 16;
        int d = row - col;
        if (d < 256 && d > -256)
          attB[(long)row * SEQ + col] = acc[mt][nt][r];
      }
}

// ---------------- softmax over band, 16 rows/block, LDS band cache ----------------
// attT2[b][nb2][n&255][mi] = att[b][m = (nb2*256)-256+mi][n], 768 mi slots
__global__ __launch_bounds__(256) void softmax_band(
    float* __restrict__ att, unsigned short* __restrict__ attT2) {
  __shared__ float e_lds[16 * 545];
  __shared__ float inv_s[16];
  int blk = blockIdx.x;          // 1024 blocks: 4 batches x 256 row-groups
  int b = blk >> 8;
  int r0 = (blk & 255) * 16;
  int tid = threadIdx.x;
  int row = tid >> 4;            // 0..15 within block
  int t16 = tid & 15;
  int i = r0 + row;
  int jbase = r0 - 272;
  float* arow = att + ((long)b * SEQ + i) * (long)SEQ;

  // phase 1a: load band window into regs, row max
  float raw[34];
  float m = -1e30f;
#pragma unroll
  for (int s = 0; s < 34; s++) {
    int jj = s * 16 + t16;
    int j = jbase + jj;
    bool ok = (j >= 0) && (j < SEQ) && (j >= i - 255) && (j <= i + 255);
    float v = ok ? arow[j] : -1e30f;
    raw[s] = v;
    m = fmaxf(m, v);
  }
#pragma unroll
  for (int off = 8; off; off >>= 1) m = fmaxf(m, __shfl_xor(m, off, 16));

  // phase 1b: exp, store to LDS, row sum
  float sum = 0.f;
#pragma unroll
  for (int s = 0; s < 34; s++) {
    int jj = s * 16 + t16;
    float e = (raw[s] > -1e29f) ? __expf(raw[s] - m) : 0.f;
    e_lds[row * 545 + jj] = e;
    sum += e;
  }
#pragma unroll
  for (int off = 8; off; off >>= 1) sum += __shfl_xor(sum, off, 16);
  float invr = 1.0f / sum;
  if (t16 == 0) inv_s[row] = invr;
  __syncthreads();

  // phase 1c: write full fp32 row (zeros outside band)
  for (int s = 0; s < 64; s++) {
    int j0 = (s * 16 + t16) * 4;
    float4 w;
    float* wp = (float*)&w;
#pragma unroll
    for (int k = 0; k < 4; k++) {
      int j = j0 + k;
      bool ok = (j >= i - 255) && (j <= i + 255);
      int jj = j - jbase;
      jj = jj < 0 ? 0 : (jj > 543 ? 543 : jj);
      wp[k] = ok ? e_lds[row * 545 + jj] * invr : 0.f;
    }
    *(float4*)(arow + j0) = w;
  }

  // phase 2: write attT2 (256-aligned band-compact transpose, 768-wide window)
  int nn = tid >> 4;
  int mi16 = tid & 15;
  int i2 = r0 + mi16;
  float inv2 = inv_s[mi16];
  int Bc = r0 & ~255;            // uniform: [r0, r0+16) never crosses a 256-boundary
  for (int s = 0; s < 48; s++) {
    int n = Bc - 256 + s * 16 + nn;
    if (n < 0 || n >= SEQ) continue;
    int mi = i2 - (n & ~255) + 256;  // always in [0,768)
    bool ok = (n >= i2 - 255) && (n <= i2 + 255);
    int jj = n - jbase;
    jj = jj < 0 ? 0 : (jj > 544 ? 544 : jj);
    float val = ok ? e_lds[mi16 * 545 + jj] * inv2 : 0.f;
    attT2[(((long)b * 16 + (n >> 8)) * 256 + (n & 255)) * 768 + mi] = f2bf(val);
  }
}

// ---------------- y[b][n][o] = sum_m att[b][m][n] * V[b][m][o], 256x256 pipelined ----------------
// A = attT2[b][nb2][256 n][768 mi], B = Vt[o][b*SEQ+m] (m contiguous), K=768.
// Phantom mi windows (m<0 or m>=SEQ) are SKIPPED at the MFMA level (block-uniform
// guard), so attT2 needs no memset; staging stays unconditional to keep the
// vmcnt ledger exact (garbage loads from allocated memory are harmless).
__global__ __launch_bounds__(512, 2) void attv256(
    const unsigned short* __restrict__ attT2, const unsigned short* __restrict__ Vt,
    unsigned short* __restrict__ yb) {
  __shared__ __align__(16) unsigned short lds[4 * 16384];
  const int KA = 768;
  const int NKT = 24;
  int b = blockIdx.z;
  int nb2 = blockIdx.x;        // 16
  int o0 = blockIdx.y * 256;   // 4
  int N0 = nb2 * 256;
  int tid = threadIdx.x;
  int lane = tid & 63;
  int wid = tid >> 6;
  int wr = wid >> 2, wc = wid & 3;

  floatx4 acc[8][4];
#pragma unroll
  for (int i = 0; i < 8; i++)
#pragma unroll
    for (int j = 0; j < 4; j++) acc[i][j] = (floatx4){0.f, 0.f, 0.f, 0.f};

  const unsigned short* Abase = attT2 + ((long)(b * 16 + nb2) * 256) * KA;
  const unsigned short* Ag = Abase + (long)(tid >> 2) * KA + (tid & 3) * 8;
  const unsigned short* Vg =
      Vt + (long)(o0 + (tid >> 2)) * (NB * SEQ) + (tid & 3) * 8;
  unsigned short* ldsW = lds + wid * 512;

  int aRd = (wr * 128 + (lane & 15)) * 32 + (lane >> 4) * 8;
  int bRd = (wc * 64 + (lane & 15)) * 32 + (lane >> 4) * 8;

  auto boff = [&](int t) {
    int mg = N0 - 256 + t * 32;
    int mc = mg < 0 ? 0 : (mg > SEQ - 32 ? SEQ - 32 : mg);
    return (long)b * SEQ + mc;
  };

#pragma unroll
  for (int tt = 0; tt < 3; tt++) {
    unsigned short* d = ldsW + tt * 16384;
    async16(Ag + tt * 32, d);
    async16(Ag + 128 * KA + tt * 32, d + 4096);
    long bo = boff(tt);
    async16(Vg + bo, d + 8192);
    async16(Vg + 128L * (NB * SEQ) + bo, d + 12288);
  }
  asm volatile("s_waitcnt vmcnt(8)" ::: "memory");
  __builtin_amdgcn_s_barrier();

  for (int t = 0; t < NKT; ++t) {
    int mg = N0 - 256 + t * 32;
    bool live = (mg > -32) && (mg < SEQ);   // block-uniform
    const unsigned short* bufA = lds + (t & 3) * 16384;
    const unsigned short* bufB = bufA + 8192;
    short8 a0f[4], b0f[4], a1f[4];
#pragma unroll
    for (int mt = 0; mt < 4; mt++)
      a0f[mt] = *(const short8*)(bufA + aRd + mt * 512);
#pragma unroll
    for (int nt = 0; nt < 4; nt++)
      b0f[nt] = *(const short8*)(bufB + bRd + nt * 512);
    if (t + 3 < NKT) {
      unsigned short* d = ldsW + ((t + 3) & 3) * 16384;
      async16(Ag + (t + 3) * 32, d);
      async16(Ag + 128 * KA + (t + 3) * 32, d + 4096);
    }
    __builtin_amdgcn_s_barrier();
    if (live) {
      __builtin_amdgcn_s_setprio(1);
#pragma unroll
      for (int mt = 0; mt < 4; mt++)
#pragma unroll
        for (int nt = 0; nt < 4; nt++)
          acc[mt][nt] = __builtin_amdgcn_mfma_f32_16x16x32_bf16(
              a0f[mt], b0f[nt], acc[mt][nt], 0, 0, 0);
      __builtin_amdgcn_s_setprio(0);
    }
    __builtin_amdgcn_s_barrier();
#pragma unroll
    for (int mt = 0; mt < 4; mt++)
      a1f[mt] = *(const short8*)(bufA + aRd + 2048 + mt * 512);
    if (t + 3 < NKT) {
      unsigned short* d = ldsW + ((t + 3) & 3) * 16384;
      long bo = boff(t + 3);
      async16(Vg + bo, d + 8192);
      async16(Vg + 128L * (NB * SEQ) + bo, d + 12288);
    }
    __builtin_amdgcn_s_barrier();
    if (live) {
      __builtin_amdgcn_s_setprio(1);
#pragma unroll
      for (int mt = 0; mt < 4; mt++)
#pragma unroll
        for (int nt = 0; nt < 4; nt++)
          acc[4 + mt][nt] = __builtin_amdgcn_mfma_f32_16x16x32_bf16(
              a1f[mt], b0f[nt], acc[4 + mt][nt], 0, 0, 0);
      __builtin_amdgcn_s_setprio(0);
    }
    if (t < NKT - 3)
      asm volatile("s_waitcnt vmcnt(8)" ::: "memory");
    else if (t == NKT - 3)
      asm volatile("s_waitcnt vmcnt(4)" ::: "memory");
    else
      asm volatile("s_waitcnt vmcnt(0)" ::: "memory");
    __builtin_amdgcn_s_barrier();
  }

  long crow = (long)b * SEQ + N0 + wr * 128 + (lane >> 4) * 4;
  int ccol = o0 + wc * 64 + (lane & 15);
#pragma unroll
  for (int mt = 0; mt < 8; mt++)
#pragma unroll
    for (int nt = 0; nt < 4; nt++)
#pragma unroll
      for (int r = 0; r < 4; r++)
        yb[(crow + mt * 16 + r) * DM + ccol + nt * 16] = f2bf(acc[mt][nt][r]);
}

extern "C" void kernel_launch(void* const* d_in, const int* in_sizes, int n_in,
                              void* d_out, int out_size, void* d_ws, size_t ws_size,
                              hipStream_t stream) {
  const float* x  = (const float*)d_in[0];
  const float* Wk = (const float*)d_in[1];
  const float* Wq = (const float*)d_in[2];
  const float* Wv = (const float*)d_in[3];
  const float* Wo = (const float*)d_in[4];
  float* outY = (float*)d_out;
  float* outAtt = outY + (long)NB * SEQ * DM;

  char* ws = (char*)d_ws;
  unsigned short* xb  = (unsigned short*)(ws + 0);            // 32 MiB (reused as yb)
  unsigned short* Kb  = (unsigned short*)(ws + 33554432);     // 32 MiB (reused as attT2)
  unsigned short* Qb  = (unsigned short*)(ws + 67108864);     // 32 MiB
  unsigned short* Vt  = (unsigned short*)(ws + 100663296);    // 32 MiB  Vt[o][b*SEQ+m]
  unsigned short* Wkb = (unsigned short*)(ws + 134217728);    // K,Q,V,O contiguous (8 MiB)
  unsigned short* Wvb = Wkb + 2097152;
  unsigned short* Wob = Wvb + 1048576;
  unsigned short* attT2 = Kb;  // alias: Kb dead after logits256
  unsigned short* yb = xb;     // alias: xb dead after Q/K/Vt GEMMs

  cvt_all<<<10240, 256, 0, stream>>>(x, Wk, Wq, Wv, Wo, xb, Wkb);

  // fused K+Q: W = [Wk;Wq] (2048x1024), grid 512 = 2 blocks/CU
  gemm256<true, 64, 8, true><<<512, 512, 0, stream>>>(
      xb, Wkb, Kb, Qb, 1.0f, QSCALE, 1024);
  // Vt = Wv * xb^T  (M=1024 -> MT=4, N=16384 -> NT=64)
  gemm256<true, 4, 64, false><<<256, 512, 0, stream>>>(
      Wvb, xb, Vt, nullptr, 1.0f, 1.0f, NB * SEQ);

  logits256<<<dim3(16, 3, NB), 512, 0, stream>>>(Qb, Kb, outAtt);
  softmax_band<<<1024, 256, 0, stream>>>(outAtt, attT2);
  attv256<<<dim3(16, 4, NB), 512, 0, stream>>>(attT2, Vt, yb);
  gemm256<false, 64, 4, false><<<256, 512, 0, stream>>>(
      yb, Wob, outY, nullptr, 1.0f, 1.0f, 1024);
}

// Round 5
// 620.936 us; speedup vs baseline: 1.1854x; 1.0308x over previous
//
#include <hip/hip_runtime.h>
#include <stdint.h>

#define SEQ 4096
#define DM  1024
#define NB  4
#define QSCALE 0.06f

typedef __attribute__((ext_vector_type(8))) short short8;
typedef __attribute__((ext_vector_type(4))) float floatx4;

__device__ __forceinline__ unsigned short f2bf(float f) {
  union { float f; unsigned int u; } v; v.f = f;
  unsigned int u = v.u;
  u += 0x7FFFu + ((u >> 16) & 1u);
  return (unsigned short)(u >> 16);
}

__device__ __forceinline__ void async16(const void* g, void* l) {
  __builtin_amdgcn_global_load_lds(
      (const __attribute__((address_space(1))) void*)g,
      (__attribute__((address_space(3))) void*)l, 16, 0, 0);
}

// ---------------- fp32 -> bf16 convert: x (8192 blks) + 4 weights (2048 blks) ----------------
__global__ void cvt_all(const float* __restrict__ x, const float* __restrict__ wk,
                        const float* __restrict__ wq, const float* __restrict__ wv,
                        const float* __restrict__ wo, unsigned short* __restrict__ xb,
                        unsigned short* __restrict__ wb) {
  int blk = blockIdx.x;
  const float* src;
  unsigned short* dst;
  int i;
  if (blk < 8192) {
    src = x; dst = xb; i = (blk * 256 + threadIdx.x) * 8;
  } else {
    int w = blk - 8192;
    int sel = w >> 9;
    src = sel == 0 ? wk : sel == 1 ? wq : sel == 2 ? wv : wo;
    dst = wb + sel * 1048576;
    i = ((w & 511) * 256 + threadIdx.x) * 8;
  }
  const float4* p = (const float4*)(src + i);
  float4 a = p[0], b = p[1];
  short8 o;
  o[0] = (short)f2bf(a.x); o[1] = (short)f2bf(a.y);
  o[2] = (short)f2bf(a.z); o[3] = (short)f2bf(a.w);
  o[4] = (short)f2bf(b.x); o[5] = (short)f2bf(b.y);
  o[6] = (short)f2bf(b.z); o[7] = (short)f2bf(b.w);
  *(short8*)(dst + i) = o;
}

// ---------------- 256x256 bf16 GEMM body, C = A * W^T, K=1024 ----------------
// 8 waves (2Mx4N), BK=32, 4 LDS buffers (128 KiB), prefetch depth 3.
// ONE barrier per K-tile: within a tile, ds_reads hit buf[t&3] and staging
// writes buf[(t+3)&3] (disjoint); buf[(t+3)&3]=buf[(t-1)&3] was fully consumed
// before the previous boundary barrier. Counted vmcnt(8) at the boundary
// leaves {t+2,t+3} (8 loads/wave) outstanding => tile t+1 landed for all
// waves after the barrier. Merged region (12 ds_read_b128 + 4 stage + 32
// independent MFMA) lets the compiler software-pipeline with fine lgkmcnt.
template <bool OUT_BF16, int MT, int NT, bool DUAL>
__device__ __forceinline__ void gemm_body(
    unsigned short* lds, int bid,
    const unsigned short* __restrict__ A, const unsigned short* __restrict__ W,
    void* __restrict__ C0, void* __restrict__ C1, float a0, float a1, long ldc) {
  const int K = 1024;
  const int NKT = 32;  // K / 32
  int tid = threadIdx.x;
  int lane = tid & 63;
  int wid = tid >> 6;
  int wr = wid >> 2, wc = wid & 3;

  // bijective XCD swizzle, nwg = MT*NT (divisible by 8)
  const int CPX = (MT * NT) >> 3;
  int raw = (bid & 7) * CPX + (bid >> 3);
  int bx = raw % MT;
  int by = raw / MT;
  long brow = (long)bx * 256;
  long bcol = (long)by * 256;

  floatx4 acc[8][4];
#pragma unroll
  for (int i = 0; i < 8; i++)
#pragma unroll
    for (int j = 0; j < 4; j++) acc[i][j] = (floatx4){0.f, 0.f, 0.f, 0.f};

  const unsigned short* Ag = A + (brow + (tid >> 2)) * K + (tid & 3) * 8;
  const unsigned short* Wg = W + (bcol + (tid >> 2)) * K + (tid & 3) * 8;
  unsigned short* ldsW = lds + wid * 512;  // wave-uniform LDS dest base

  int aRd = (wr * 128 + (lane & 15)) * 32 + (lane >> 4) * 8;
  int bRd = (wc * 64 + (lane & 15)) * 32 + (lane >> 4) * 8;

#pragma unroll
  for (int tt = 0; tt < 3; tt++) {
    unsigned short* d = ldsW + tt * 16384;
    const unsigned short* a = Ag + tt * 32;
    const unsigned short* w = Wg + tt * 32;
    async16(a, d);
    async16(a + 128 * K, d + 4096);
    async16(w, d + 8192);
    async16(w + 128 * K, d + 12288);
  }
  asm volatile("s_waitcnt vmcnt(8)" ::: "memory");
  __builtin_amdgcn_s_barrier();

  for (int t = 0; t < NKT; ++t) {
    const unsigned short* bufA = lds + (t & 3) * 16384;
    const unsigned short* bufB = bufA + 8192;
    short8 a0f[4], b0f[4], a1f[4];
#pragma unroll
    for (int mt = 0; mt < 4; mt++)
      a0f[mt] = *(const short8*)(bufA + aRd + mt * 512);
#pragma unroll
    for (int nt = 0; nt < 4; nt++)
      b0f[nt] = *(const short8*)(bufB + bRd + nt * 512);
#pragma unroll
    for (int mt = 0; mt < 4; mt++)
      a1f[mt] = *(const short8*)(bufA + aRd + 2048 + mt * 512);
    if (t + 3 < NKT) {  // stage all 4 halves of tile t+3
      unsigned short* d = ldsW + ((t + 3) & 3) * 16384;
      const unsigned short* a = Ag + (t + 3) * 32;
      const unsigned short* w = Wg + (t + 3) * 32;
      async16(a, d);
      async16(a + 128 * K, d + 4096);
      async16(w, d + 8192);
      async16(w + 128 * K, d + 12288);
    }
    __builtin_amdgcn_s_setprio(1);
#pragma unroll
    for (int mt = 0; mt < 4; mt++)
#pragma unroll
      for (int nt = 0; nt < 4; nt++)
        acc[mt][nt] = __builtin_amdgcn_mfma_f32_16x16x32_bf16(
            a0f[mt], b0f[nt], acc[mt][nt], 0, 0, 0);
#pragma unroll
    for (int mt = 0; mt < 4; mt++)
#pragma unroll
      for (int nt = 0; nt < 4; nt++)
        acc[4 + mt][nt] = __builtin_amdgcn_mfma_f32_16x16x32_bf16(
            a1f[mt], b0f[nt], acc[4 + mt][nt], 0, 0, 0);
    __builtin_amdgcn_s_setprio(0);
    if (t < NKT - 3)
      asm volatile("s_waitcnt vmcnt(8)" ::: "memory");
    else if (t == NKT - 3)
      asm volatile("s_waitcnt vmcnt(4)" ::: "memory");
    else
      asm volatile("s_waitcnt vmcnt(0)" ::: "memory");
    __builtin_amdgcn_s_barrier();
  }

  void* Cp;
  float alpha;
  long cc;
  if (DUAL && by >= NT / 2) {
    Cp = C1; alpha = a1; cc = bcol - (long)(NT / 2) * 256;
  } else {
    Cp = C0; alpha = a0; cc = bcol;
  }
  long crow = brow + wr * 128 + (lane >> 4) * 4;
  long ccol = cc + wc * 64 + (lane & 15);
#pragma unroll
  for (int mt = 0; mt < 8; mt++)
#pragma unroll
    for (int nt = 0; nt < 4; nt++)
#pragma unroll
      for (int r = 0; r < 4; r++) {
        float v = acc[mt][nt][r] * alpha;
        long idx = (crow + mt * 16 + r) * ldc + ccol + nt * 16;
        if (OUT_BF16)
          ((unsigned short*)Cp)[idx] = f2bf(v);
        else
          ((float*)Cp)[idx] = v;
      }
}

// fused projections: blocks 0-511 = K+Q (DUAL), 512-767 = Vt
__global__ __launch_bounds__(512, 2) void proj_fused(
    const unsigned short* __restrict__ xb, const unsigned short* __restrict__ Wkb,
    const unsigned short* __restrict__ Wvb, unsigned short* __restrict__ Kb,
    unsigned short* __restrict__ Qb, unsigned short* __restrict__ Vt) {
  __shared__ __align__(16) unsigned short lds[4 * 16384];
  if (blockIdx.x < 512)
    gemm_body<true, 64, 8, true>(lds, blockIdx.x, xb, Wkb, Kb, Qb, 1.0f, QSCALE,
                                 1024);
  else
    gemm_body<true, 4, 64, false>(lds, blockIdx.x - 512, Wvb, xb, Vt, nullptr,
                                  1.0f, 1.0f, (long)NB * SEQ);
}

// output projection y*Wo^T (fp32 out)
__global__ __launch_bounds__(512, 2) void gemm_wo(
    const unsigned short* __restrict__ yb, const unsigned short* __restrict__ Wob,
    float* __restrict__ outY) {
  __shared__ __align__(16) unsigned short lds[4 * 16384];
  gemm_body<false, 64, 4, false>(lds, blockIdx.x, yb, Wob, outY, nullptr, 1.0f,
                                 1.0f, 1024);
}

// ---------------- banded logits via the same 256x256 pipeline ----------------
// grid (16 n-tiles, 3 m-offsets {-256,0,+256}, NB); fp32 band-masked epilogue.
__global__ __launch_bounds__(512, 2) void logits256(
    const unsigned short* __restrict__ Qb, const unsigned short* __restrict__ Kb,
    float* __restrict__ att) {
  int b = blockIdx.z;
  int n0 = blockIdx.x * 256;
  int m0 = n0 + ((int)blockIdx.y - 1) * 256;
  if (m0 < 0 || m0 >= SEQ) return;
  __shared__ __align__(16) unsigned short lds[4 * 16384];
  const int K = 1024;
  const int NKT = 32;
  int tid = threadIdx.x;
  int lane = tid & 63;
  int wid = tid >> 6;
  int wr = wid >> 2, wc = wid & 3;

  floatx4 acc[8][4];
#pragma unroll
  for (int i = 0; i < 8; i++)
#pragma unroll
    for (int j = 0; j < 4; j++) acc[i][j] = (floatx4){0.f, 0.f, 0.f, 0.f};

  const unsigned short* Ag =
      Qb + ((long)b * SEQ + n0 + (tid >> 2)) * K + (tid & 3) * 8;
  const unsigned short* Wg =
      Kb + ((long)b * SEQ + m0 + (tid >> 2)) * K + (tid & 3) * 8;
  unsigned short* ldsW = lds + wid * 512;

  int aRd = (wr * 128 + (lane & 15)) * 32 + (lane >> 4) * 8;
  int bRd = (wc * 64 + (lane & 15)) * 32 + (lane >> 4) * 8;

#pragma unroll
  for (int tt = 0; tt < 3; tt++) {
    unsigned short* d = ldsW + tt * 16384;
    const unsigned short* a = Ag + tt * 32;
    const unsigned short* w = Wg + tt * 32;
    async16(a, d);
    async16(a + 128 * K, d + 4096);
    async16(w, d + 8192);
    async16(w + 128 * K, d + 12288);
  }
  asm volatile("s_waitcnt vmcnt(8)" ::: "memory");
  __builtin_amdgcn_s_barrier();

  for (int t = 0; t < NKT; ++t) {
    const unsigned short* bufA = lds + (t & 3) * 16384;
    const unsigned short* bufB = bufA + 8192;
    short8 a0f[4], b0f[4], a1f[4];
#pragma unroll
    for (int mt = 0; mt < 4; mt++)
      a0f[mt] = *(const short8*)(bufA + aRd + mt * 512);
#pragma unroll
    for (int nt = 0; nt < 4; nt++)
      b0f[nt] = *(const short8*)(bufB + bRd + nt * 512);
#pragma unroll
    for (int mt = 0; mt < 4; mt++)
      a1f[mt] = *(const short8*)(bufA + aRd + 2048 + mt * 512);
    if (t + 3 < NKT) {
      unsigned short* d = ldsW + ((t + 3) & 3) * 16384;
      const unsigned short* a = Ag + (t + 3) * 32;
      const unsigned short* w = Wg + (t + 3) * 32;
      async16(a, d);
      async16(a + 128 * K, d + 4096);
      async16(w, d + 8192);
      async16(w + 128 * K, d + 12288);
    }
    __builtin_amdgcn_s_setprio(1);
#pragma unroll
    for (int mt = 0; mt < 4; mt++)
#pragma unroll
      for (int nt = 0; nt < 4; nt++)
        acc[mt][nt] = __builtin_amdgcn_mfma_f32_16x16x32_bf16(
            a0f[mt], b0f[nt], acc[mt][nt], 0, 0, 0);
#pragma unroll
    for (int mt = 0; mt < 4; mt++)
#pragma unroll
      for (int nt = 0; nt < 4; nt++)
        acc[4 + mt][nt] = __builtin_amdgcn_mfma_f32_16x16x32_bf16(
            a1f[mt], b0f[nt], acc[4 + mt][nt], 0, 0, 0);
    __builtin_amdgcn_s_setprio(0);
    if (t < NKT - 3)
      asm volatile("s_waitcnt vmcnt(8)" ::: "memory");
    else if (t == NKT - 3)
      asm volatile("s_waitcnt vmcnt(4)" ::: "memory");
    else
      asm volatile("s_waitcnt vmcnt(0)" ::: "memory");
    __builtin_amdgcn_s_barrier();
  }

  float* attB = att + (long)b * SEQ * SEQ;
  int crow = n0 + wr * 128 + (lane >> 4) * 4;
  int ccol = m0 + wc * 64 + (lane & 15);
#pragma unroll
  for (int mt = 0; mt < 8; mt++)
#pragma unroll
    for (int nt = 0; nt < 4; nt++)
#pragma unroll
      for (int r = 0; r < 4; r++) {
        int row = crow + mt * 16 + r;
        int col = ccol + nt * 16;
        int d = row - col;
        if (d < 256 && d > -256)
          attB[(long)row * SEQ + col] = acc[mt][nt][r];
      }
}

// ---------------- softmax over band, 16 rows/block, LDS band cache ----------------
// attT2[b][nb2][n&255][mi] = att[b][m = (nb2*256)-256+mi][n], 768 mi slots
__global__ __launch_bounds__(256) void softmax_band(
    float* __restrict__ att, unsigned short* __restrict__ attT2) {
  __shared__ float e_lds[16 * 545];
  __shared__ float inv_s[16];
  int blk = blockIdx.x;          // 1024 blocks: 4 batches x 256 row-groups
  int b = blk >> 8;
  int r0 = (blk & 255) * 16;
  int tid = threadIdx.x;
  int row = tid >> 4;            // 0..15 within block
  int t16 = tid & 15;
  int i = r0 + row;
  int jbase = r0 - 272;
  float* arow = att + ((long)b * SEQ + i) * (long)SEQ;

  // phase 1a: load band window into regs, row max
  float raw[34];
  float m = -1e30f;
#pragma unroll
  for (int s = 0; s < 34; s++) {
    int jj = s * 16 + t16;
    int j = jbase + jj;
    bool ok = (j >= 0) && (j < SEQ) && (j >= i - 255) && (j <= i + 255);
    float v = ok ? arow[j] : -1e30f;
    raw[s] = v;
    m = fmaxf(m, v);
  }
#pragma unroll
  for (int off = 8; off; off >>= 1) m = fmaxf(m, __shfl_xor(m, off, 16));

  // phase 1b: exp, store to LDS, row sum
  float sum = 0.f;
#pragma unroll
  for (int s = 0; s < 34; s++) {
    int jj = s * 16 + t16;
    float e = (raw[s] > -1e29f) ? __expf(raw[s] - m) : 0.f;
    e_lds[row * 545 + jj] = e;
    sum += e;
  }
#pragma unroll
  for (int off = 8; off; off >>= 1) sum += __shfl_xor(sum, off, 16);
  float invr = 1.0f / sum;
  if (t16 == 0) inv_s[row] = invr;
  __syncthreads();

  // phase 1c: write full fp32 row (zeros outside band)
  for (int s = 0; s < 64; s++) {
    int j0 = (s * 16 + t16) * 4;
    float4 w;
    float* wp = (float*)&w;
#pragma unroll
    for (int k = 0; k < 4; k++) {
      int j = j0 + k;
      bool ok = (j >= i - 255) && (j <= i + 255);
      int jj = j - jbase;
      jj = jj < 0 ? 0 : (jj > 543 ? 543 : jj);
      wp[k] = ok ? e_lds[row * 545 + jj] * invr : 0.f;
    }
    *(float4*)(arow + j0) = w;
  }

  // phase 2: write attT2 (256-aligned band-compact transpose, 768-wide window)
  int nn = tid >> 4;
  int mi16 = tid & 15;
  int i2 = r0 + mi16;
  float inv2 = inv_s[mi16];
  int Bc = r0 & ~255;            // uniform: [r0, r0+16) never crosses a 256-boundary
  for (int s = 0; s < 48; s++) {
    int n = Bc - 256 + s * 16 + nn;
    if (n < 0 || n >= SEQ) continue;
    int mi = i2 - (n & ~255) + 256;  // always in [0,768)
    bool ok = (n >= i2 - 255) && (n <= i2 + 255);
    int jj = n - jbase;
    jj = jj < 0 ? 0 : (jj > 544 ? 544 : jj);
    float val = ok ? e_lds[mi16 * 545 + jj] * inv2 : 0.f;
    attT2[(((long)b * 16 + (n >> 8)) * 256 + (n & 255)) * 768 + mi] = f2bf(val);
  }
}

// ---------------- y[b][n][o] = sum_m att[b][m][n] * V[b][m][o], 256x256 pipelined ----------------
// A = attT2[b][nb2][256 n][768 mi], B = Vt[o][b*SEQ+m] (m contiguous), K=768.
// Phantom mi windows skipped at the MFMA level (block-uniform guard); staging
// unconditional to keep the vmcnt ledger exact.
__global__ __launch_bounds__(512, 2) void attv256(
    const unsigned short* __restrict__ attT2, const unsigned short* __restrict__ Vt,
    unsigned short* __restrict__ yb) {
  __shared__ __align__(16) unsigned short lds[4 * 16384];
  const int KA = 768;
  const int NKT = 24;
  int b = blockIdx.z;
  int nb2 = blockIdx.x;        // 16
  int o0 = blockIdx.y * 256;   // 4
  int N0 = nb2 * 256;
  int tid = threadIdx.x;
  int lane = tid & 63;
  int wid = tid >> 6;
  int wr = wid >> 2, wc = wid & 3;

  floatx4 acc[8][4];
#pragma unroll
  for (int i = 0; i < 8; i++)
#pragma unroll
    for (int j = 0; j < 4; j++) acc[i][j] = (floatx4){0.f, 0.f, 0.f, 0.f};

  const unsigned short* Abase = attT2 + ((long)(b * 16 + nb2) * 256) * KA;
  const unsigned short* Ag = Abase + (long)(tid >> 2) * KA + (tid & 3) * 8;
  const unsigned short* Vg =
      Vt + (long)(o0 + (tid >> 2)) * (NB * SEQ) + (tid & 3) * 8;
  unsigned short* ldsW = lds + wid * 512;

  int aRd = (wr * 128 + (lane & 15)) * 32 + (lane >> 4) * 8;
  int bRd = (wc * 64 + (lane & 15)) * 32 + (lane >> 4) * 8;

  auto boff = [&](int t) {
    int mg = N0 - 256 + t * 32;
    int mc = mg < 0 ? 0 : (mg > SEQ - 32 ? SEQ - 32 : mg);
    return (long)b * SEQ + mc;
  };

#pragma unroll
  for (int tt = 0; tt < 3; tt++) {
    unsigned short* d = ldsW + tt * 16384;
    async16(Ag + tt * 32, d);
    async16(Ag + 128 * KA + tt * 32, d + 4096);
    long bo = boff(tt);
    async16(Vg + bo, d + 8192);
    async16(Vg + 128L * (NB * SEQ) + bo, d + 12288);
  }
  asm volatile("s_waitcnt vmcnt(8)" ::: "memory");
  __builtin_amdgcn_s_barrier();

  for (int t = 0; t < NKT; ++t) {
    int mg = N0 - 256 + t * 32;
    bool live = (mg > -32) && (mg < SEQ);   // block-uniform
    const unsigned short* bufA = lds + (t & 3) * 16384;
    const unsigned short* bufB = bufA + 8192;
    short8 a0f[4], b0f[4], a1f[4];
#pragma unroll
    for (int mt = 0; mt < 4; mt++)
      a0f[mt] = *(const short8*)(bufA + aRd + mt * 512);
#pragma unroll
    for (int nt = 0; nt < 4; nt++)
      b0f[nt] = *(const short8*)(bufB + bRd + nt * 512);
#pragma unroll
    for (int mt = 0; mt < 4; mt++)
      a1f[mt] = *(const short8*)(bufA + aRd + 2048 + mt * 512);
    if (t + 3 < NKT) {
      unsigned short* d = ldsW + ((t + 3) & 3) * 16384;
      long bo = boff(t + 3);
      async16(Ag + (t + 3) * 32, d);
      async16(Ag + 128 * KA + (t + 3) * 32, d + 4096);
      async16(Vg + bo, d + 8192);
      async16(Vg + 128L * (NB * SEQ) + bo, d + 12288);
    }
    if (live) {
      __builtin_amdgcn_s_setprio(1);
#pragma unroll
      for (int mt = 0; mt < 4; mt++)
#pragma unroll
        for (int nt = 0; nt < 4; nt++)
          acc[mt][nt] = __builtin_amdgcn_mfma_f32_16x16x32_bf16(
              a0f[mt], b0f[nt], acc[mt][nt], 0, 0, 0);
#pragma unroll
      for (int mt = 0; mt < 4; mt++)
#pragma unroll
        for (int nt = 0; nt < 4; nt++)
          acc[4 + mt][nt] = __builtin_amdgcn_mfma_f32_16x16x32_bf16(
              a1f[mt], b0f[nt], acc[4 + mt][nt], 0, 0, 0);
      __builtin_amdgcn_s_setprio(0);
    }
    if (t < NKT - 3)
      asm volatile("s_waitcnt vmcnt(8)" ::: "memory");
    else if (t == NKT - 3)
      asm volatile("s_waitcnt vmcnt(4)" ::: "memory");
    else
      asm volatile("s_waitcnt vmcnt(0)" ::: "memory");
    __builtin_amdgcn_s_barrier();
  }

  long crow = (long)b * SEQ + N0 + wr * 128 + (lane >> 4) * 4;
  int ccol = o0 + wc * 64 + (lane & 15);
#pragma unroll
  for (int mt = 0; mt < 8; mt++)
#pragma unroll
    for (int nt = 0; nt < 4; nt++)
#pragma unroll
      for (int r = 0; r < 4; r++)
        yb[(crow + mt * 16 + r) * DM + ccol + nt * 16] = f2bf(acc[mt][nt][r]);
}

extern "C" void kernel_launch(void* const* d_in, const int* in_sizes, int n_in,
                              void* d_out, int out_size, void* d_ws, size_t ws_size,
                              hipStream_t stream) {
  const float* x  = (const float*)d_in[0];
  const float* Wk = (const float*)d_in[1];
  const float* Wq = (const float*)d_in[2];
  const float* Wv = (const float*)d_in[3];
  const float* Wo = (const float*)d_in[4];
  float* outY = (float*)d_out;
  float* outAtt = outY + (long)NB * SEQ * DM;

  char* ws = (char*)d_ws;
  unsigned short* xb  = (unsigned short*)(ws + 0);            // 32 MiB (reused as yb)
  unsigned short* Kb  = (unsigned short*)(ws + 33554432);     // 32 MiB (reused as attT2)
  unsigned short* Qb  = (unsigned short*)(ws + 67108864);     // 32 MiB
  unsigned short* Vt  = (unsigned short*)(ws + 100663296);    // 32 MiB  Vt[o][b*SEQ+m]
  unsigned short* Wkb = (unsigned short*)(ws + 134217728);    // K,Q,V,O contiguous (8 MiB)
  unsigned short* Wvb = Wkb + 2097152;
  unsigned short* Wob = Wvb + 1048576;
  unsigned short* attT2 = Kb;  // alias: Kb dead after logits256
  unsigned short* yb = xb;     // alias: xb dead after projections

  cvt_all<<<10240, 256, 0, stream>>>(x, Wk, Wq, Wv, Wo, xb, Wkb);
  proj_fused<<<768, 512, 0, stream>>>(xb, Wkb, Wvb, Kb, Qb, Vt);
  logits256<<<dim3(16, 3, NB), 512, 0, stream>>>(Qb, Kb, outAtt);
  softmax_band<<<1024, 256, 0, stream>>>(outAtt, attT2);
  attv256<<<dim3(16, 4, NB), 512, 0, stream>>>(attT2, Vt, yb);
  gemm_wo<<<256, 512, 0, stream>>>(yb, Wob, outY);
}

// Round 6
// 620.587 us; speedup vs baseline: 1.1861x; 1.0006x over previous
//
#include <hip/hip_runtime.h>
#include <stdint.h>

#define SEQ 4096
#define DM  1024
#define NB  4
#define QSCALE 0.06f

typedef __attribute__((ext_vector_type(8))) short short8;
typedef __attribute__((ext_vector_type(4))) float floatx4;

__device__ __forceinline__ unsigned short f2bf(float f) {
  union { float f; unsigned int u; } v; v.f = f;
  unsigned int u = v.u;
  u += 0x7FFFu + ((u >> 16) & 1u);
  return (unsigned short)(u >> 16);
}

__device__ __forceinline__ void async16(const void* g, void* l) {
  __builtin_amdgcn_global_load_lds(
      (const __attribute__((address_space(1))) void*)g,
      (__attribute__((address_space(3))) void*)l, 16, 0, 0);
}

// ---------------- fp32 -> bf16 convert: x (8192 blks) + 4 weights (2048 blks) ----------------
__global__ void cvt_all(const float* __restrict__ x, const float* __restrict__ wk,
                        const float* __restrict__ wq, const float* __restrict__ wv,
                        const float* __restrict__ wo, unsigned short* __restrict__ xb,
                        unsigned short* __restrict__ wb) {
  int blk = blockIdx.x;
  const float* src;
  unsigned short* dst;
  int i;
  if (blk < 8192) {
    src = x; dst = xb; i = (blk * 256 + threadIdx.x) * 8;
  } else {
    int w = blk - 8192;
    int sel = w >> 9;
    src = sel == 0 ? wk : sel == 1 ? wq : sel == 2 ? wv : wo;
    dst = wb + sel * 1048576;
    i = ((w & 511) * 256 + threadIdx.x) * 8;
  }
  const float4* p = (const float4*)(src + i);
  float4 a = p[0], b = p[1];
  short8 o;
  o[0] = (short)f2bf(a.x); o[1] = (short)f2bf(a.y);
  o[2] = (short)f2bf(a.z); o[3] = (short)f2bf(a.w);
  o[4] = (short)f2bf(b.x); o[5] = (short)f2bf(b.y);
  o[6] = (short)f2bf(b.z); o[7] = (short)f2bf(b.w);
  *(short8*)(dst + i) = o;
}

// ---------------- 256x256 bf16 GEMM body, C = A * W^T, K=1024 ----------------
// 8 waves (2Mx4N), BK=32, 4 LDS buffers (128 KiB), prefetch depth 3,
// ONE barrier per K-tile, counted vmcnt(8) (never 0 in steady state).
// LDS bank swizzle (T2-analog for 64-B rows): the fragment read pattern
// (16 lanes x rows at 64-B stride, b128) is an 8-way bank conflict on the
// linear layout (m98: 1.7e7 conflicts on this lineage). Fix: XOR row bits
// 1-2 into the 16B-chunk index, applied on BOTH sides (rule 21):
//   write: thread t stages global chunk (t&3)^((t>>3)&3) of its row into
//          linear LDS dest (global_load_lds requires linear dest);
//   read : aRd/bRd ^= (((lane&15)>>1)&3)<<3  (row bits 1-2 are invariant
//          under mt*512 / +2048 / wr / wc offsets, so the XOR folds into
//          the offset init -- zero runtime cost).
// Data permutation is identical on write and read => bitwise-identical math.
template <bool OUT_BF16, int MT, int NT, bool DUAL>
__device__ __forceinline__ void gemm_body(
    unsigned short* lds, int bid,
    const unsigned short* __restrict__ A, const unsigned short* __restrict__ W,
    void* __restrict__ C0, void* __restrict__ C1, float a0, float a1, long ldc) {
  const int K = 1024;
  const int NKT = 32;  // K / 32
  int tid = threadIdx.x;
  int lane = tid & 63;
  int wid = tid >> 6;
  int wr = wid >> 2, wc = wid & 3;

  // bijective XCD swizzle, nwg = MT*NT (divisible by 8)
  const int CPX = (MT * NT) >> 3;
  int raw = (bid & 7) * CPX + (bid >> 3);
  int bx = raw % MT;
  int by = raw / MT;
  long brow = (long)bx * 256;
  long bcol = (long)by * 256;

  floatx4 acc[8][4];
#pragma unroll
  for (int i = 0; i < 8; i++)
#pragma unroll
    for (int j = 0; j < 4; j++) acc[i][j] = (floatx4){0.f, 0.f, 0.f, 0.f};

  // staging with pre-swizzled source chunk
  int schunk = (tid & 3) ^ ((tid >> 3) & 3);
  const unsigned short* Ag = A + (brow + (tid >> 2)) * K + schunk * 8;
  const unsigned short* Wg = W + (bcol + (tid >> 2)) * K + schunk * 8;
  unsigned short* ldsW = lds + wid * 512;  // wave-uniform LDS dest base

  int aRd = (wr * 128 + (lane & 15)) * 32 + (lane >> 4) * 8;
  int bRd = (wc * 64 + (lane & 15)) * 32 + (lane >> 4) * 8;
  int rsw = (((lane & 15) >> 1) & 3) << 3;
  aRd ^= rsw;
  bRd ^= rsw;

#pragma unroll
  for (int tt = 0; tt < 3; tt++) {
    unsigned short* d = ldsW + tt * 16384;
    const unsigned short* a = Ag + tt * 32;
    const unsigned short* w = Wg + tt * 32;
    async16(a, d);
    async16(a + 128 * K, d + 4096);
    async16(w, d + 8192);
    async16(w + 128 * K, d + 12288);
  }
  asm volatile("s_waitcnt vmcnt(8)" ::: "memory");
  __builtin_amdgcn_s_barrier();

  for (int t = 0; t < NKT; ++t) {
    const unsigned short* bufA = lds + (t & 3) * 16384;
    const unsigned short* bufB = bufA + 8192;
    short8 a0f[4], b0f[4], a1f[4];
#pragma unroll
    for (int mt = 0; mt < 4; mt++)
      a0f[mt] = *(const short8*)(bufA + aRd + mt * 512);
#pragma unroll
    for (int nt = 0; nt < 4; nt++)
      b0f[nt] = *(const short8*)(bufB + bRd + nt * 512);
#pragma unroll
    for (int mt = 0; mt < 4; mt++)
      a1f[mt] = *(const short8*)(bufA + aRd + 2048 + mt * 512);
    if (t + 3 < NKT) {  // stage all 4 halves of tile t+3
      unsigned short* d = ldsW + ((t + 3) & 3) * 16384;
      const unsigned short* a = Ag + (t + 3) * 32;
      const unsigned short* w = Wg + (t + 3) * 32;
      async16(a, d);
      async16(a + 128 * K, d + 4096);
      async16(w, d + 8192);
      async16(w + 128 * K, d + 12288);
    }
    __builtin_amdgcn_s_setprio(1);
#pragma unroll
    for (int mt = 0; mt < 4; mt++)
#pragma unroll
      for (int nt = 0; nt < 4; nt++)
        acc[mt][nt] = __builtin_amdgcn_mfma_f32_16x16x32_bf16(
            a0f[mt], b0f[nt], acc[mt][nt], 0, 0, 0);
#pragma unroll
    for (int mt = 0; mt < 4; mt++)
#pragma unroll
      for (int nt = 0; nt < 4; nt++)
        acc[4 + mt][nt] = __builtin_amdgcn_mfma_f32_16x16x32_bf16(
            a1f[mt], b0f[nt], acc[4 + mt][nt], 0, 0, 0);
    __builtin_amdgcn_s_setprio(0);
    if (t < NKT - 3)
      asm volatile("s_waitcnt vmcnt(8)" ::: "memory");
    else if (t == NKT - 3)
      asm volatile("s_waitcnt vmcnt(4)" ::: "memory");
    else
      asm volatile("s_waitcnt vmcnt(0)" ::: "memory");
    __builtin_amdgcn_s_barrier();
  }

  void* Cp;
  float alpha;
  long cc;
  if (DUAL && by >= NT / 2) {
    Cp = C1; alpha = a1; cc = bcol - (long)(NT / 2) * 256;
  } else {
    Cp = C0; alpha = a0; cc = bcol;
  }
  long crow = brow + wr * 128 + (lane >> 4) * 4;
  long ccol = cc + wc * 64 + (lane & 15);
#pragma unroll
  for (int mt = 0; mt < 8; mt++)
#pragma unroll
    for (int nt = 0; nt < 4; nt++)
#pragma unroll
      for (int r = 0; r < 4; r++) {
        float v = acc[mt][nt][r] * alpha;
        long idx = (crow + mt * 16 + r) * ldc + ccol + nt * 16;
        if (OUT_BF16)
          ((unsigned short*)Cp)[idx] = f2bf(v);
        else
          ((float*)Cp)[idx] = v;
      }
}

// fused projections: blocks 0-511 = K+Q (DUAL), 512-767 = Vt
__global__ __launch_bounds__(512, 2) void proj_fused(
    const unsigned short* __restrict__ xb, const unsigned short* __restrict__ Wkb,
    const unsigned short* __restrict__ Wvb, unsigned short* __restrict__ Kb,
    unsigned short* __restrict__ Qb, unsigned short* __restrict__ Vt) {
  __shared__ __align__(16) unsigned short lds[4 * 16384];
  if (blockIdx.x < 512)
    gemm_body<true, 64, 8, true>(lds, blockIdx.x, xb, Wkb, Kb, Qb, 1.0f, QSCALE,
                                 1024);
  else
    gemm_body<true, 4, 64, false>(lds, blockIdx.x - 512, Wvb, xb, Vt, nullptr,
                                  1.0f, 1.0f, (long)NB * SEQ);
}

// output projection y*Wo^T (fp32 out)
__global__ __launch_bounds__(512, 2) void gemm_wo(
    const unsigned short* __restrict__ yb, const unsigned short* __restrict__ Wob,
    float* __restrict__ outY) {
  __shared__ __align__(16) unsigned short lds[4 * 16384];
  gemm_body<false, 64, 4, false>(lds, blockIdx.x, yb, Wob, outY, nullptr, 1.0f,
                                 1.0f, 1024);
}

// ---------------- banded logits via the same 256x256 pipeline ----------------
// grid (16 n-tiles, 3 m-offsets {-256,0,+256}, NB); fp32 band-masked epilogue.
__global__ __launch_bounds__(512, 2) void logits256(
    const unsigned short* __restrict__ Qb, const unsigned short* __restrict__ Kb,
    float* __restrict__ att) {
  int b = blockIdx.z;
  int n0 = blockIdx.x * 256;
  int m0 = n0 + ((int)blockIdx.y - 1) * 256;
  if (m0 < 0 || m0 >= SEQ) return;
  __shared__ __align__(16) unsigned short lds[4 * 16384];
  const int K = 1024;
  const int NKT = 32;
  int tid = threadIdx.x;
  int lane = tid & 63;
  int wid = tid >> 6;
  int wr = wid >> 2, wc = wid & 3;

  floatx4 acc[8][4];
#pragma unroll
  for (int i = 0; i < 8; i++)
#pragma unroll
    for (int j = 0; j < 4; j++) acc[i][j] = (floatx4){0.f, 0.f, 0.f, 0.f};

  int schunk = (tid & 3) ^ ((tid >> 3) & 3);
  const unsigned short* Ag =
      Qb + ((long)b * SEQ + n0 + (tid >> 2)) * K + schunk * 8;
  const unsigned short* Wg =
      Kb + ((long)b * SEQ + m0 + (tid >> 2)) * K + schunk * 8;
  unsigned short* ldsW = lds + wid * 512;

  int aRd = (wr * 128 + (lane & 15)) * 32 + (lane >> 4) * 8;
  int bRd = (wc * 64 + (lane & 15)) * 32 + (lane >> 4) * 8;
  int rsw = (((lane & 15) >> 1) & 3) << 3;
  aRd ^= rsw;
  bRd ^= rsw;

#pragma unroll
  for (int tt = 0; tt < 3; tt++) {
    unsigned short* d = ldsW + tt * 16384;
    const unsigned short* a = Ag + tt * 32;
    const unsigned short* w = Wg + tt * 32;
    async16(a, d);
    async16(a + 128 * K, d + 4096);
    async16(w, d + 8192);
    async16(w + 128 * K, d + 12288);
  }
  asm volatile("s_waitcnt vmcnt(8)" ::: "memory");
  __builtin_amdgcn_s_barrier();

  for (int t = 0; t < NKT; ++t) {
    const unsigned short* bufA = lds + (t & 3) * 16384;
    const unsigned short* bufB = bufA + 8192;
    short8 a0f[4], b0f[4], a1f[4];
#pragma unroll
    for (int mt = 0; mt < 4; mt++)
      a0f[mt] = *(const short8*)(bufA + aRd + mt * 512);
#pragma unroll
    for (int nt = 0; nt < 4; nt++)
      b0f[nt] = *(const short8*)(bufB + bRd + nt * 512);
#pragma unroll
    for (int mt = 0; mt < 4; mt++)
      a1f[mt] = *(const short8*)(bufA + aRd + 2048 + mt * 512);
    if (t + 3 < NKT) {
      unsigned short* d = ldsW + ((t + 3) & 3) * 16384;
      const unsigned short* a = Ag + (t + 3) * 32;
      const unsigned short* w = Wg + (t + 3) * 32;
      async16(a, d);
      async16(a + 128 * K, d + 4096);
      async16(w, d + 8192);
      async16(w + 128 * K, d + 12288);
    }
    __builtin_amdgcn_s_setprio(1);
#pragma unroll
    for (int mt = 0; mt < 4; mt++)
#pragma unroll
      for (int nt = 0; nt < 4; nt++)
        acc[mt][nt] = __builtin_amdgcn_mfma_f32_16x16x32_bf16(
            a0f[mt], b0f[nt], acc[mt][nt], 0, 0, 0);
#pragma unroll
    for (int mt = 0; mt < 4; mt++)
#pragma unroll
      for (int nt = 0; nt < 4; nt++)
        acc[4 + mt][nt] = __builtin_amdgcn_mfma_f32_16x16x32_bf16(
            a1f[mt], b0f[nt], acc[4 + mt][nt], 0, 0, 0);
    __builtin_amdgcn_s_setprio(0);
    if (t < NKT - 3)
      asm volatile("s_waitcnt vmcnt(8)" ::: "memory");
    else if (t == NKT - 3)
      asm volatile("s_waitcnt vmcnt(4)" ::: "memory");
    else
      asm volatile("s_waitcnt vmcnt(0)" ::: "memory");
    __builtin_amdgcn_s_barrier();
  }

  float* attB = att + (long)b * SEQ * SEQ;
  int crow = n0 + wr * 128 + (lane >> 4) * 4;
  int ccol = m0 + wc * 64 + (lane & 15);
#pragma unroll
  for (int mt = 0; mt < 8; mt++)
#pragma unroll
    for (int nt = 0; nt < 4; nt++)
#pragma unroll
      for (int r = 0; r < 4; r++) {
        int row = crow + mt * 16 + r;
        int col = ccol + nt * 16;
        int d = row - col;
        if (d < 256 && d > -256)
          attB[(long)row * SEQ + col] = acc[mt][nt][r];
      }
}

// ---------------- softmax over band, 16 rows/block, LDS band cache ----------------
// attT2[b][nb2][n&255][mi] = att[b][m = (nb2*256)-256+mi][n], 768 mi slots
__global__ __launch_bounds__(256) void softmax_band(
    float* __restrict__ att, unsigned short* __restrict__ attT2) {
  __shared__ float e_lds[16 * 545];
  __shared__ float inv_s[16];
  int blk = blockIdx.x;          // 1024 blocks: 4 batches x 256 row-groups
  int b = blk >> 8;
  int r0 = (blk & 255) * 16;
  int tid = threadIdx.x;
  int row = tid >> 4;            // 0..15 within block
  int t16 = tid & 15;
  int i = r0 + row;
  int jbase = r0 - 272;
  float* arow = att + ((long)b * SEQ + i) * (long)SEQ;

  // phase 1a: load band window into regs, row max
  float raw[34];
  float m = -1e30f;
#pragma unroll
  for (int s = 0; s < 34; s++) {
    int jj = s * 16 + t16;
    int j = jbase + jj;
    bool ok = (j >= 0) && (j < SEQ) && (j >= i - 255) && (j <= i + 255);
    float v = ok ? arow[j] : -1e30f;
    raw[s] = v;
    m = fmaxf(m, v);
  }
#pragma unroll
  for (int off = 8; off; off >>= 1) m = fmaxf(m, __shfl_xor(m, off, 16));

  // phase 1b: exp, store to LDS, row sum
  float sum = 0.f;
#pragma unroll
  for (int s = 0; s < 34; s++) {
    int jj = s * 16 + t16;
    float e = (raw[s] > -1e29f) ? __expf(raw[s] - m) : 0.f;
    e_lds[row * 545 + jj] = e;
    sum += e;
  }
#pragma unroll
  for (int off = 8; off; off >>= 1) sum += __shfl_xor(sum, off, 16);
  float invr = 1.0f / sum;
  if (t16 == 0) inv_s[row] = invr;
  __syncthreads();

  // phase 1c: write full fp32 row (zeros outside band)
  for (int s = 0; s < 64; s++) {
    int j0 = (s * 16 + t16) * 4;
    float4 w;
    float* wp = (float*)&w;
#pragma unroll
    for (int k = 0; k < 4; k++) {
      int j = j0 + k;
      bool ok = (j >= i - 255) && (j <= i + 255);
      int jj = j - jbase;
      jj = jj < 0 ? 0 : (jj > 543 ? 543 : jj);
      wp[k] = ok ? e_lds[row * 545 + jj] * invr : 0.f;
    }
    *(float4*)(arow + j0) = w;
  }

  // phase 2: write attT2 (256-aligned band-compact transpose, 768-wide window)
  int nn = tid >> 4;
  int mi16 = tid & 15;
  int i2 = r0 + mi16;
  float inv2 = inv_s[mi16];
  int Bc = r0 & ~255;            // uniform: [r0, r0+16) never crosses a 256-boundary
  for (int s = 0; s < 48; s++) {
    int n = Bc - 256 + s * 16 + nn;
    if (n < 0 || n >= SEQ) continue;
    int mi = i2 - (n & ~255) + 256;  // always in [0,768)
    bool ok = (n >= i2 - 255) && (n <= i2 + 255);
    int jj = n - jbase;
    jj = jj < 0 ? 0 : (jj > 544 ? 544 : jj);
    float val = ok ? e_lds[mi16 * 545 + jj] * inv2 : 0.f;
    attT2[(((long)b * 16 + (n >> 8)) * 256 + (n & 255)) * 768 + mi] = f2bf(val);
  }
}

// ---------------- y[b][n][o] = sum_m att[b][m][n] * V[b][m][o], 256x256 pipelined ----------------
// A = attT2[b][nb2][256 n][768 mi], B = Vt[o][b*SEQ+m] (m contiguous), K=768.
// Phantom mi windows skipped at the MFMA level (block-uniform guard); staging
// unconditional to keep the vmcnt ledger exact. Same LDS swizzle as gemm_body.
__global__ __launch_bounds__(512, 2) void attv256(
    const unsigned short* __restrict__ attT2, const unsigned short* __restrict__ Vt,
    unsigned short* __restrict__ yb) {
  __shared__ __align__(16) unsigned short lds[4 * 16384];
  const int KA = 768;
  const int NKT = 24;
  int b = blockIdx.z;
  int nb2 = blockIdx.x;        // 16
  int o0 = blockIdx.y * 256;   // 4
  int N0 = nb2 * 256;
  int tid = threadIdx.x;
  int lane = tid & 63;
  int wid = tid >> 6;
  int wr = wid >> 2, wc = wid & 3;

  floatx4 acc[8][4];
#pragma unroll
  for (int i = 0; i < 8; i++)
#pragma unroll
    for (int j = 0; j < 4; j++) acc[i][j] = (floatx4){0.f, 0.f, 0.f, 0.f};

  int schunk = (tid & 3) ^ ((tid >> 3) & 3);
  const unsigned short* Abase = attT2 + ((long)(b * 16 + nb2) * 256) * KA;
  const unsigned short* Ag = Abase + (long)(tid >> 2) * KA + schunk * 8;
  const unsigned short* Vg =
      Vt + (long)(o0 + (tid >> 2)) * (NB * SEQ) + schunk * 8;
  unsigned short* ldsW = lds + wid * 512;

  int aRd = (wr * 128 + (lane & 15)) * 32 + (lane >> 4) * 8;
  int bRd = (wc * 64 + (lane & 15)) * 32 + (lane >> 4) * 8;
  int rsw = (((lane & 15) >> 1) & 3) << 3;
  aRd ^= rsw;
  bRd ^= rsw;

  auto boff = [&](int t) {
    int mg = N0 - 256 + t * 32;
    int mc = mg < 0 ? 0 : (mg > SEQ - 32 ? SEQ - 32 : mg);
    return (long)b * SEQ + mc;
  };

#pragma unroll
  for (int tt = 0; tt < 3; tt++) {
    unsigned short* d = ldsW + tt * 16384;
    async16(Ag + tt * 32, d);
    async16(Ag + 128 * KA + tt * 32, d + 4096);
    long bo = boff(tt);
    async16(Vg + bo, d + 8192);
    async16(Vg + 128L * (NB * SEQ) + bo, d + 12288);
  }
  asm volatile("s_waitcnt vmcnt(8)" ::: "memory");
  __builtin_amdgcn_s_barrier();

  for (int t = 0; t < NKT; ++t) {
    int mg = N0 - 256 + t * 32;
    bool live = (mg > -32) && (mg < SEQ);   // block-uniform
    const unsigned short* bufA = lds + (t & 3) * 16384;
    const unsigned short* bufB = bufA + 8192;
    short8 a0f[4], b0f[4], a1f[4];
#pragma unroll
    for (int mt = 0; mt < 4; mt++)
      a0f[mt] = *(const short8*)(bufA + aRd + mt * 512);
#pragma unroll
    for (int nt = 0; nt < 4; nt++)
      b0f[nt] = *(const short8*)(bufB + bRd + nt * 512);
#pragma unroll
    for (int mt = 0; mt < 4; mt++)
      a1f[mt] = *(const short8*)(bufA + aRd + 2048 + mt * 512);
    if (t + 3 < NKT) {
      unsigned short* d = ldsW + ((t + 3) & 3) * 16384;
      long bo = boff(t + 3);
      async16(Ag + (t + 3) * 32, d);
      async16(Ag + 128 * KA + (t + 3) * 32, d + 4096);
      async16(Vg + bo, d + 8192);
      async16(Vg + 128L * (NB * SEQ) + bo, d + 12288);
    }
    if (live) {
      __builtin_amdgcn_s_setprio(1);
#pragma unroll
      for (int mt = 0; mt < 4; mt++)
#pragma unroll
        for (int nt = 0; nt < 4; nt++)
          acc[mt][nt] = __builtin_amdgcn_mfma_f32_16x16x32_bf16(
              a0f[mt], b0f[nt], acc[mt][nt], 0, 0, 0);
#pragma unroll
      for (int mt = 0; mt < 4; mt++)
#pragma unroll
        for (int nt = 0; nt < 4; nt++)
          acc[4 + mt][nt] = __builtin_amdgcn_mfma_f32_16x16x32_bf16(
              a1f[mt], b0f[nt], acc[4 + mt][nt], 0, 0, 0);
      __builtin_amdgcn_s_setprio(0);
    }
    if (t < NKT - 3)
      asm volatile("s_waitcnt vmcnt(8)" ::: "memory");
    else if (t == NKT - 3)
      asm volatile("s_waitcnt vmcnt(4)" ::: "memory");
    else
      asm volatile("s_waitcnt vmcnt(0)" ::: "memory");
    __builtin_amdgcn_s_barrier();
  }

  long crow = (long)b * SEQ + N0 + wr * 128 + (lane >> 4) * 4;
  int ccol = o0 + wc * 64 + (lane & 15);
#pragma unroll
  for (int mt = 0; mt < 8; mt++)
#pragma unroll
    for (int nt = 0; nt < 4; nt++)
#pragma unroll
      for (int r = 0; r < 4; r++)
        yb[(crow + mt * 16 + r) * DM + ccol + nt * 16] = f2bf(acc[mt][nt][r]);
}

extern "C" void kernel_launch(void* const* d_in, const int* in_sizes, int n_in,
                              void* d_out, int out_size, void* d_ws, size_t ws_size,
                              hipStream_t stream) {
  const float* x  = (const float*)d_in[0];
  const float* Wk = (const float*)d_in[1];
  const float* Wq = (const float*)d_in[2];
  const float* Wv = (const float*)d_in[3];
  const float* Wo = (const float*)d_in[4];
  float* outY = (float*)d_out;
  float* outAtt = outY + (long)NB * SEQ * DM;

  char* ws = (char*)d_ws;
  unsigned short* xb  = (unsigned short*)(ws + 0);            // 32 MiB (reused as yb)
  unsigned short* Kb  = (unsigned short*)(ws + 33554432);     // 32 MiB (reused as attT2)
  unsigned short* Qb  = (unsigned short*)(ws + 67108864);     // 32 MiB
  unsigned short* Vt  = (unsigned short*)(ws + 100663296);    // 32 MiB  Vt[o][b*SEQ+m]
  unsigned short* Wkb = (unsigned short*)(ws + 134217728);    // K,Q,V,O contiguous (8 MiB)
  unsigned short* Wvb = Wkb + 2097152;
  unsigned short* Wob = Wvb + 1048576;
  unsigned short* attT2 = Kb;  // alias: Kb dead after logits256
  unsigned short* yb = xb;     // alias: xb dead after projections

  cvt_all<<<10240, 256, 0, stream>>>(x, Wk, Wq, Wv, Wo, xb, Wkb);
  proj_fused<<<768, 512, 0, stream>>>(xb, Wkb, Wvb, Kb, Qb, Vt);
  logits256<<<dim3(16, 3, NB), 512, 0, stream>>>(Qb, Kb, outAtt);
  softmax_band<<<1024, 256, 0, stream>>>(outAtt, attT2);
  attv256<<<dim3(16, 4, NB), 512, 0, stream>>>(attT2, Vt, yb);
  gemm_wo<<<256, 512, 0, stream>>>(yb, Wob, outY);
}